// Round 1
// baseline (1150.535 us; speedup 1.0000x reference)
//
#include <hip/hip_runtime.h>
#include <math.h>

#define BB 8192
#define NF 1024
#define KKc 2016
#define DD 64

// ---------------- Kernel 1: v = silu(x) @ W^T + b ----------------
#define BM 128
#define BN 128
#define BKr 16
#define XST 132   // LDS stride for [k][row] tiles (128 + 4 pad)

__global__ __launch_bounds__(256, 2)
void gemm_silu_kernel(const float* __restrict__ x, const float* __restrict__ W,
                      const float* __restrict__ bias, float* __restrict__ v) {
  __shared__ float xs[BKr * XST];
  __shared__ float wl[BKr * XST];
  const int tid = threadIdx.x;
  const int tx = tid & 15, ty = tid >> 4;
  const int c0g = blockIdx.x * BN;
  const int m0 = blockIdx.y * BM;
  const int lrow = tid >> 2;          // 0..63
  const int lu = (tid & 3) << 2;      // 0,4,8,12

  float acc[2][2][4][4];
#pragma unroll
  for (int a = 0; a < 2; a++)
#pragma unroll
    for (int b = 0; b < 2; b++)
#pragma unroll
      for (int i = 0; i < 4; i++)
#pragma unroll
        for (int j = 0; j < 4; j++) acc[a][b][i][j] = 0.f;

  for (int n0 = 0; n0 < NF; n0 += BKr) {
#pragma unroll
    for (int p = 0; p < 2; p++) {
      const int row = lrow + 64 * p;
      float4 xv = *(const float4*)(x + (size_t)(m0 + row) * NF + n0 + lu);
      float xa[4] = {xv.x, xv.y, xv.z, xv.w};
#pragma unroll
      for (int u = 0; u < 4; u++) {
        const float val = xa[u];
        const float sl = val / (1.f + __expf(-val));   // silu
        xs[(lu + u) * XST + row] = sl;
      }
      const int wr = c0g + row;
      float4 wv = make_float4(0.f, 0.f, 0.f, 0.f);
      if (wr < KKc) wv = *(const float4*)(W + (size_t)wr * NF + n0 + lu);
      float wa[4] = {wv.x, wv.y, wv.z, wv.w};
#pragma unroll
      for (int u = 0; u < 4; u++) wl[(lu + u) * XST + row] = wa[u];
    }
    __syncthreads();
#pragma unroll
    for (int k0 = 0; k0 < BKr; k0 += 4) {
#pragma unroll
      for (int kk = 0; kk < 4; kk++) {
        const float* xr = xs + (k0 + kk) * XST;
        const float* wr_ = wl + (k0 + kk) * XST;
        float4 t;
        t = *(const float4*)(xr + 4 * ty);       float a0[4] = {t.x, t.y, t.z, t.w};
        t = *(const float4*)(xr + 64 + 4 * ty);  float a1[4] = {t.x, t.y, t.z, t.w};
        t = *(const float4*)(wr_ + 4 * tx);      float b0[4] = {t.x, t.y, t.z, t.w};
        t = *(const float4*)(wr_ + 64 + 4 * tx); float b1[4] = {t.x, t.y, t.z, t.w};
#pragma unroll
        for (int i = 0; i < 4; i++)
#pragma unroll
          for (int j = 0; j < 4; j++) {
            acc[0][0][i][j] = fmaf(a0[i], b0[j], acc[0][0][i][j]);
            acc[0][1][i][j] = fmaf(a0[i], b1[j], acc[0][1][i][j]);
            acc[1][0][i][j] = fmaf(a1[i], b0[j], acc[1][0][i][j]);
            acc[1][1][i][j] = fmaf(a1[i], b1[j], acc[1][1][i][j]);
          }
      }
    }
    __syncthreads();
  }
  // epilogue: add bias, store v
#pragma unroll
  for (int rb = 0; rb < 2; rb++)
#pragma unroll
    for (int ii = 0; ii < 4; ii++) {
      const int row = m0 + rb * 64 + 4 * ty + ii;
#pragma unroll
      for (int cb = 0; cb < 2; cb++) {
        const int c = c0g + cb * 64 + 4 * tx;
        if (c < KKc) {
          float4 bb = *(const float4*)(bias + c);
          float4 o;
          o.x = acc[rb][cb][ii][0] + bb.x;
          o.y = acc[rb][cb][ii][1] + bb.y;
          o.z = acc[rb][cb][ii][2] + bb.z;
          o.w = acc[rb][cb][ii][3] + bb.w;
          *(float4*)(v + (size_t)row * KKc + c) = o;
        }
      }
    }
}

// ---------------- Kernel 2: R = expm(skew(v_row)) ----------------
#define EST 68   // 64 + 4 pad, multiple of 4 for aligned float4 LDS ops

__device__ __forceinline__ void mm_acc64(const float* __restrict__ A, const float* __restrict__ Bm,
                                         float acc[4][4], int r0, int c0) {
#pragma unroll 4
  for (int k0 = 0; k0 < 64; k0 += 4) {
    float4 t;
    float a[4][4];
#pragma unroll
    for (int i = 0; i < 4; i++) {
      t = *(const float4*)(A + (r0 + i) * EST + k0);
      a[i][0] = t.x; a[i][1] = t.y; a[i][2] = t.z; a[i][3] = t.w;
    }
    float b[4][4];
#pragma unroll
    for (int kk = 0; kk < 4; kk++) {
      t = *(const float4*)(Bm + (k0 + kk) * EST + c0);
      b[kk][0] = t.x; b[kk][1] = t.y; b[kk][2] = t.z; b[kk][3] = t.w;
    }
#pragma unroll
    for (int i = 0; i < 4; i++)
#pragma unroll
      for (int kk = 0; kk < 4; kk++)
#pragma unroll
        for (int j = 0; j < 4; j++)
          acc[i][j] = fmaf(a[i][kk], b[kk][j], acc[i][j]);
  }
}

__device__ __forceinline__ void mm_store64(float* __restrict__ D, const float* __restrict__ A,
                                           const float* __restrict__ Bm, int r0, int c0) {
  float acc[4][4];
#pragma unroll
  for (int i = 0; i < 4; i++)
#pragma unroll
    for (int j = 0; j < 4; j++) acc[i][j] = 0.f;
  mm_acc64(A, Bm, acc, r0, c0);
#pragma unroll
  for (int i = 0; i < 4; i++) {
    float4 o;
    o.x = acc[i][0]; o.y = acc[i][1]; o.z = acc[i][2]; o.w = acc[i][3];
    *(float4*)(D + (r0 + i) * EST + c0) = o;
  }
  __syncthreads();
}

__global__ __launch_bounds__(256, 3)
void expm_kernel(const float* __restrict__ v, float* __restrict__ out) {
  __shared__ float MA[DD * EST];
  __shared__ float MBs[DD * EST];
  __shared__ float MCs[DD * EST];
  __shared__ float red[256];
  const int tid = threadIdx.x;
  const int bid = blockIdx.x;
  const int tx = tid & 15, ty = tid >> 4;
  const int r0 = 4 * ty, c0 = 4 * tx;
  const float* vr = v + (size_t)bid * KKc;

  // stage v row into MCs (coalesced), then build skew A into MA
  for (int k = tid; k < KKc; k += 256) MCs[k] = vr[k];
  __syncthreads();

  float fsum = 0.f;
  for (int idx = tid; idx < 4096; idx += 256) {
    const int i = idx >> 6, j = idx & 63;
    float val = 0.f;
    if (i < j)      val =  MCs[(i * (127 - i)) / 2 + (j - i - 1)];
    else if (i > j) val = -MCs[(j * (127 - j)) / 2 + (i - j - 1)];
    MA[i * EST + j] = val;
    fsum += val * val;
  }
  red[tid] = fsum;
  __syncthreads();
  for (int off = 128; off > 0; off >>= 1) {
    if (tid < off) red[tid] += red[tid + off];
    __syncthreads();
  }
  const float nf = sqrtf(red[0]);          // ||A||_F >= ||A||_2
  int s = 0;
  if (nf > 1.f) { s = (int)ceilf(log2f(nf)); if (s > 25) s = 25; }
  const float sc = exp2f(-(float)s);
  __syncthreads();
  for (int idx = tid; idx < 4096; idx += 256) {
    const int i = idx >> 6, j = idx & 63;
    MA[i * EST + j] *= sc;                 // X = A / 2^s
  }
  __syncthreads();

  // X2 = X*X ; X4 = X2*X2
  mm_store64(MBs, MA, MA, r0, c0);
  mm_store64(MCs, MBs, MBs, r0, c0);

  const float c2 = 0.5f, c4 = 1.f / 24.f, c6 = 1.f / 720.f, c8 = 1.f / 40320.f;
  const float d3 = 1.f / 6.f, d5 = 1.f / 120.f, d7 = 1.f / 5040.f;

  float rE[4][4], rd3[4][4], rc6[4][4];
  // pass1: harvest X2 terms, overwrite MBs with S2 = d5*I + d7*X2
#pragma unroll
  for (int i = 0; i < 4; i++)
#pragma unroll
    for (int j = 0; j < 4; j++) {
      const int r = r0 + i, c = c0 + j;
      const float x2 = MBs[r * EST + c], x4 = MCs[r * EST + c];
      const float dg = (r == c) ? 1.f : 0.f;
      rE[i][j]  = dg + c2 * x2 + c4 * x4;
      rd3[i][j] = d3 * x2;
      rc6[i][j] = c6 * x2;
      MBs[r * EST + c] = d5 * dg + d7 * x2;
    }
  __syncthreads();

  // rT2 = X4 * S2
  float rT2[4][4];
#pragma unroll
  for (int i = 0; i < 4; i++)
#pragma unroll
    for (int j = 0; j < 4; j++) rT2[i][j] = 0.f;
  mm_acc64(MCs, MBs, rT2, r0, c0);
  __syncthreads();

  // S1 = c6*X2 + c8*X4 into MBs
#pragma unroll
  for (int i = 0; i < 4; i++)
#pragma unroll
    for (int j = 0; j < 4; j++) {
      const int r = r0 + i, c = c0 + j;
      MBs[r * EST + c] = rc6[i][j] + c8 * MCs[r * EST + c];
    }
  __syncthreads();

  // rE += X4 * S1   (even part complete)
  mm_acc64(MCs, MBs, rE, r0, c0);
  __syncthreads();

  // S3 = I + d3*X2 + T2 into MBs
#pragma unroll
  for (int i = 0; i < 4; i++)
#pragma unroll
    for (int j = 0; j < 4; j++) {
      const int r = r0 + i, c = c0 + j;
      const float dg = (r == c) ? 1.f : 0.f;
      MBs[r * EST + c] = dg + rd3[i][j] + rT2[i][j];
    }
  __syncthreads();

  // rO = X * S3  (odd part)
  float rO[4][4];
#pragma unroll
  for (int i = 0; i < 4; i++)
#pragma unroll
    for (int j = 0; j < 4; j++) rO[i][j] = 0.f;
  mm_acc64(MA, MBs, rO, r0, c0);
  __syncthreads();

  // R0 = E + O into MBs
#pragma unroll
  for (int i = 0; i < 4; i++)
#pragma unroll
    for (int j = 0; j < 4; j++) {
      const int r = r0 + i, c = c0 + j;
      MBs[r * EST + c] = rE[i][j] + rO[i][j];
    }
  __syncthreads();

  // s squarings, ping-pong MBs <-> MCs
  float* cur = MBs;
  float* oth = MCs;
  for (int t = 0; t < s; t++) {
    mm_store64(oth, cur, cur, r0, c0);
    float* tmp = cur; cur = oth; oth = tmp;
  }

  // write out (coalesced float4)
  float* ob = out + (size_t)bid * 4096;
  for (int g = tid; g < 1024; g += 256) {
    const int i = g >> 4, grp = g & 15;
    float4 t = *(const float4*)(cur + i * EST + 4 * grp);
    *(float4*)(ob + 4 * g) = t;
  }
}

extern "C" void kernel_launch(void* const* d_in, const int* in_sizes, int n_in,
                              void* d_out, int out_size, void* d_ws, size_t ws_size,
                              hipStream_t stream) {
  const float* x = (const float*)d_in[0];
  const float* W = (const float*)d_in[1];
  const float* bias = (const float*)d_in[2];
  float* out = (float*)d_out;
  float* v = (float*)d_ws;   // 8192*2016*4 = 66 MB scratch

  dim3 g1((KKc + BN - 1) / BN, BB / BM);
  gemm_silu_kernel<<<g1, dim3(256), 0, stream>>>(x, W, bias, v);
  expm_kernel<<<dim3(BB), dim3(256), 0, stream>>>(v, out);
}

// Round 2
// 741.968 us; speedup vs baseline: 1.5507x; 1.5507x over previous
//
#include <hip/hip_runtime.h>
#include <math.h>

#define BB 8192
#define NF 1024
#define KKc 2016
#define DD 64

// ---------------- Kernel 1: v = silu(x) @ W^T + b  (unchanged) ----------------
#define BM 128
#define BN 128
#define BKr 16
#define XST 132

__global__ __launch_bounds__(256, 2)
void gemm_silu_kernel(const float* __restrict__ x, const float* __restrict__ W,
                      const float* __restrict__ bias, float* __restrict__ v) {
  __shared__ float xs[BKr * XST];
  __shared__ float wl[BKr * XST];
  const int tid = threadIdx.x;
  const int tx = tid & 15, ty = tid >> 4;
  const int c0g = blockIdx.x * BN;
  const int m0 = blockIdx.y * BM;
  const int lrow = tid >> 2;
  const int lu = (tid & 3) << 2;

  float acc[2][2][4][4];
#pragma unroll
  for (int a = 0; a < 2; a++)
#pragma unroll
    for (int b = 0; b < 2; b++)
#pragma unroll
      for (int i = 0; i < 4; i++)
#pragma unroll
        for (int j = 0; j < 4; j++) acc[a][b][i][j] = 0.f;

  for (int n0 = 0; n0 < NF; n0 += BKr) {
#pragma unroll
    for (int p = 0; p < 2; p++) {
      const int row = lrow + 64 * p;
      float4 xv = *(const float4*)(x + (size_t)(m0 + row) * NF + n0 + lu);
      float xa[4] = {xv.x, xv.y, xv.z, xv.w};
#pragma unroll
      for (int u = 0; u < 4; u++) {
        const float val = xa[u];
        const float sl = val / (1.f + __expf(-val));
        xs[(lu + u) * XST + row] = sl;
      }
      const int wr = c0g + row;
      float4 wv = make_float4(0.f, 0.f, 0.f, 0.f);
      if (wr < KKc) wv = *(const float4*)(W + (size_t)wr * NF + n0 + lu);
      float wa[4] = {wv.x, wv.y, wv.z, wv.w};
#pragma unroll
      for (int u = 0; u < 4; u++) wl[(lu + u) * XST + row] = wa[u];
    }
    __syncthreads();
#pragma unroll
    for (int k0 = 0; k0 < BKr; k0 += 4) {
#pragma unroll
      for (int kk = 0; kk < 4; kk++) {
        const float* xr = xs + (k0 + kk) * XST;
        const float* wr_ = wl + (k0 + kk) * XST;
        float4 t;
        t = *(const float4*)(xr + 4 * ty);       float a0[4] = {t.x, t.y, t.z, t.w};
        t = *(const float4*)(xr + 64 + 4 * ty);  float a1[4] = {t.x, t.y, t.z, t.w};
        t = *(const float4*)(wr_ + 4 * tx);      float b0[4] = {t.x, t.y, t.z, t.w};
        t = *(const float4*)(wr_ + 64 + 4 * tx); float b1[4] = {t.x, t.y, t.z, t.w};
#pragma unroll
        for (int i = 0; i < 4; i++)
#pragma unroll
          for (int j = 0; j < 4; j++) {
            acc[0][0][i][j] = fmaf(a0[i], b0[j], acc[0][0][i][j]);
            acc[0][1][i][j] = fmaf(a0[i], b1[j], acc[0][1][i][j]);
            acc[1][0][i][j] = fmaf(a1[i], b0[j], acc[1][0][i][j]);
            acc[1][1][i][j] = fmaf(a1[i], b1[j], acc[1][1][i][j]);
          }
      }
    }
    __syncthreads();
  }
#pragma unroll
  for (int rb = 0; rb < 2; rb++)
#pragma unroll
    for (int ii = 0; ii < 4; ii++) {
      const int row = m0 + rb * 64 + 4 * ty + ii;
#pragma unroll
      for (int cb = 0; cb < 2; cb++) {
        const int c = c0g + cb * 64 + 4 * tx;
        if (c < KKc) {
          float4 bb = *(const float4*)(bias + c);
          float4 o;
          o.x = acc[rb][cb][ii][0] + bb.x;
          o.y = acc[rb][cb][ii][1] + bb.y;
          o.z = acc[rb][cb][ii][2] + bb.z;
          o.w = acc[rb][cb][ii][3] + bb.w;
          *(float4*)(v + (size_t)row * KKc + c) = o;
        }
      }
    }
}

// ---------------- Kernel 2: R = expm(skew(v_row)) via split-bf16 MFMA ----------------

typedef __attribute__((ext_vector_type(4))) float f32x4;
typedef __attribute__((ext_vector_type(4))) unsigned int u32x4;
typedef __attribute__((ext_vector_type(8))) short s16x8;

union FragU { u32x4 u; s16x8 s; };

// swizzled dword address inside a 64x64 u32 matrix buffer
__device__ __forceinline__ int daddr(int row, int col) {
  return (row << 6) | ((((col >> 2) ^ (row & 15)) << 2) | (col & 3));
}

// split fp32 -> packed (bf16_hi | bf16_lo<<16), RNE both halves
__device__ __forceinline__ unsigned pack_split(float v) {
  unsigned uv = __float_as_uint(v);
  unsigned hi16 = (uv + 0x7fffu + ((uv >> 16) & 1u)) >> 16;
  float fhi = __uint_as_float(hi16 << 16);
  float lo = v - fhi;
  unsigned ul = __float_as_uint(lo);
  unsigned lo16 = (ul + 0x7fffu + ((ul >> 16) & 1u)) >> 16;
  return hi16 | (lo16 << 16);
}

// A-pattern fragment: lane holds M[row][32*kb + 8*g + e], e=0..7 (row = 16*t + (l&15))
__device__ __forceinline__ void load_rowfrag(const unsigned* P, int row, int kb, int g,
                                             FragU& fh, FragU& fl, bool neg) {
  const int sw = row & 15;
  const int q0 = (kb << 3) + (g << 1);
  const unsigned* base = P + (row << 6);
  u32x4 A0 = *(const u32x4*)(base + ((q0 ^ sw) << 2));
  u32x4 A1 = *(const u32x4*)(base + (((q0 + 1) ^ sw) << 2));
  unsigned u[8] = {A0[0], A0[1], A0[2], A0[3], A1[0], A1[1], A1[2], A1[3]};
  const unsigned xm = neg ? 0x80008000u : 0u;
#pragma unroll
  for (int r = 0; r < 4; r++) {
    fh.u[r] = (((u[2 * r] & 0xffffu) | (u[2 * r + 1] << 16)) ^ xm);
    fl.u[r] = (((u[2 * r] >> 16) | (u[2 * r + 1] & 0xffff0000u)) ^ xm);
  }
}

// B-pattern fragment from a NON-symmetric matrix: lane holds M[32*kb+8*g+e][n]
__device__ __forceinline__ void load_colfrag(const unsigned* P, int n, int kb, int g,
                                             FragU& fh, FragU& fl) {
  const int kbase = (kb << 5) + (g << 3);
  const int nq = n >> 2, ne = n & 3;
  unsigned u[8];
#pragma unroll
  for (int e = 0; e < 8; e++) {
    const int k = kbase + e;
    u[e] = P[(k << 6) | (((nq ^ (k & 15)) << 2) | ne)];
  }
#pragma unroll
  for (int r = 0; r < 4; r++) {
    fh.u[r] = ((u[2 * r] & 0xffffu) | (u[2 * r + 1] << 16));
    fl.u[r] = ((u[2 * r] >> 16) | (u[2 * r + 1] & 0xffff0000u));
  }
}

// acc += A * B (2x2 tiles of 16x16 per wave). NEGB: B-frag = -(row-read) (skew source).
// COLB: B-frags via strided column reads (non-symmetric source). NPASS: 1=hi only, 3=split.
template<int NPASS, bool NEGB, bool COLB>
__device__ __forceinline__ void mat_mm(const unsigned* Ab, const unsigned* Bb,
                                       f32x4 acc[2][2], int wi, int wj, int g, int m) {
#pragma unroll
  for (int kb = 0; kb < 2; kb++) {
    FragU bh[2], bl[2];
#pragma unroll
    for (int b = 0; b < 2; b++) {
      const int n = ((((wj << 1) + b) << 4) | m);
      if (COLB) load_colfrag(Bb, n, kb, g, bh[b], bl[b]);
      else      load_rowfrag(Bb, n, kb, g, bh[b], bl[b], NEGB);
    }
#pragma unroll
    for (int a = 0; a < 2; a++) {
      FragU ah, al;
      const int row = ((((wi << 1) + a) << 4) | m);
      load_rowfrag(Ab, row, kb, g, ah, al, false);
#pragma unroll
      for (int b = 0; b < 2; b++) {
        acc[a][b] = __builtin_amdgcn_mfma_f32_16x16x32_bf16(ah.s, bh[b].s, acc[a][b], 0, 0, 0);
        if (NPASS == 3) {
          acc[a][b] = __builtin_amdgcn_mfma_f32_16x16x32_bf16(ah.s, bl[b].s, acc[a][b], 0, 0, 0);
          acc[a][b] = __builtin_amdgcn_mfma_f32_16x16x32_bf16(al.s, bh[b].s, acc[a][b], 0, 0, 0);
        }
      }
    }
  }
}

__device__ __forceinline__ void pack_write(unsigned* P, const f32x4 v[2][2],
                                           int wi, int wj, int g, int m) {
#pragma unroll
  for (int a = 0; a < 2; a++)
#pragma unroll
    for (int b = 0; b < 2; b++)
#pragma unroll
      for (int i = 0; i < 4; i++) {
        const int row = (((wi << 1) + a) << 4) + (g << 2) + i;
        const int col = (((wj << 1) + b) << 4) + m;
        P[daddr(row, col)] = pack_split(v[a][b][i]);
      }
}

__global__ __launch_bounds__(256, 3)
void expm_kernel(const float* __restrict__ v, float* __restrict__ out) {
  __shared__ __align__(16) unsigned B0s[4096];
  __shared__ __align__(16) unsigned B1s[4096];
  __shared__ __align__(16) unsigned B2s[4096];
  __shared__ float red[4];
  const int tid = threadIdx.x;
  const int bid = blockIdx.x;
  const int l = tid & 63, w = tid >> 6;
  const int g = l >> 4, m = l & 15;
  const int wi = w >> 1, wj = w & 1;

  // 1. stage v row into B2 (raw floats)
  {
    float* vbw = (float*)B2s;
    const float* vr = v + (size_t)bid * KKc;
#pragma unroll
    for (int it = 0; it < 8; it++) {
      const int idx = tid + 256 * it;
      if (idx < KKc) vbw[idx] = vr[idx];
    }
  }
  __syncthreads();

  // 2. build skew values (regs) + Frobenius norm
  float vals[16];
  float fs = 0.f;
  {
    const float* vb = (const float*)B2s;
#pragma unroll
    for (int rr = 0; rr < 16; rr++) {
      const int row = rr * 4 + w;
      const int col = l;
      float val = 0.f;
      if (row < col)      val =  vb[(row * (127 - row)) / 2 + col - row - 1];
      else if (row > col) val = -vb[(col * (127 - col)) / 2 + row - col - 1];
      vals[rr] = val;
      fs += val * val;
    }
  }
#pragma unroll
  for (int k = 1; k < 64; k <<= 1) fs += __shfl_xor(fs, k, 64);
  if (l == 0) red[w] = fs;
  __syncthreads();
  const float nf = sqrtf(red[0] + red[1] + red[2] + red[3]);
  int s = 0;
  if (nf > 1.f) { s = (int)ceilf(log2f(nf)); if (s > 30) s = 30; if (s < 0) s = 0; }
  const float sc = exp2f(-(float)s);
  __syncthreads();

  // 3. write X = A * 2^-s, packed hi/lo, into B0
#pragma unroll
  for (int rr = 0; rr < 16; rr++) {
    const int row = rr * 4 + w;
    B0s[daddr(row, l)] = pack_split(vals[rr] * sc);
  }
  __syncthreads();

  const f32x4 zz = {0.f, 0.f, 0.f, 0.f};
  f32x4 acc[2][2];

  // 4. X2 = X*X  (B-frag from skew X: negated row-read)
  acc[0][0] = zz; acc[0][1] = zz; acc[1][0] = zz; acc[1][1] = zz;
  mat_mm<3, true, false>(B0s, B0s, acc, wi, wj, g, m);
  f32x4 rX2[2][2];
  rX2[0][0] = acc[0][0]; rX2[0][1] = acc[0][1]; rX2[1][0] = acc[1][0]; rX2[1][1] = acc[1][1];
  pack_write(B1s, acc, wi, wj, g, m);
  __syncthreads();

  // 5. X4 = X2*X2 (symmetric)
  acc[0][0] = zz; acc[0][1] = zz; acc[1][0] = zz; acc[1][1] = zz;
  mat_mm<3, false, false>(B1s, B1s, acc, wi, wj, g, m);
  // fold E, S3 partials; free rX2
  f32x4 rEp[2][2], rS3[2][2];
#pragma unroll
  for (int a = 0; a < 2; a++)
#pragma unroll
    for (int b = 0; b < 2; b++)
#pragma unroll
      for (int i = 0; i < 4; i++) {
        const int row = (((wi << 1) + a) << 4) + (g << 2) + i;
        const int col = (((wj << 1) + b) << 4) + m;
        const float dg = (row == col) ? 1.f : 0.f;
        const float x2 = rX2[a][b][i], x4 = acc[a][b][i];
        rEp[a][b][i] = dg + 0.5f * x2 + (1.f / 24.f) * x4;
        rS3[a][b][i] = dg + (1.f / 6.f) * x2 + (1.f / 120.f) * x4;
      }
  pack_write(B2s, acc, wi, wj, g, m);   // X4 -> B2
  __syncthreads();

  // 6. X6 = X4*X2 (1-pass hi)
  acc[0][0] = zz; acc[0][1] = zz; acc[1][0] = zz; acc[1][1] = zz;
  mat_mm<1, false, false>(B2s, B1s, acc, wi, wj, g, m);
#pragma unroll
  for (int a = 0; a < 2; a++)
#pragma unroll
    for (int b = 0; b < 2; b++)
#pragma unroll
      for (int i = 0; i < 4; i++) {
        rEp[a][b][i] += (1.f / 720.f) * acc[a][b][i];
        rS3[a][b][i] += (1.f / 5040.f) * acc[a][b][i];
      }

  // 7. X8 = X4*X4 (1-pass hi)
  acc[0][0] = zz; acc[0][1] = zz; acc[1][0] = zz; acc[1][1] = zz;
  mat_mm<1, false, false>(B2s, B2s, acc, wi, wj, g, m);
#pragma unroll
  for (int a = 0; a < 2; a++)
#pragma unroll
    for (int b = 0; b < 2; b++)
#pragma unroll
      for (int i = 0; i < 4; i++)
        rEp[a][b][i] += (1.f / 40320.f) * acc[a][b][i];
  __syncthreads();                       // all reads of B2 (X4) done
  pack_write(B2s, rS3, wi, wj, g, m);    // S3 -> B2 (symmetric)
  __syncthreads();

  // 8. R0 = E + X*S3  (acc init = E)
  acc[0][0] = rEp[0][0]; acc[0][1] = rEp[0][1]; acc[1][0] = rEp[1][0]; acc[1][1] = rEp[1][1];
  mat_mm<3, false, false>(B0s, B2s, acc, wi, wj, g, m);

  // 9. s squarings (R not symmetric: column B-frags)
  for (int t = 0; t < s; t++) {
    unsigned* dst = (t & 1) ? B2s : B1s;
    pack_write(dst, acc, wi, wj, g, m);
    __syncthreads();
    acc[0][0] = zz; acc[0][1] = zz; acc[1][0] = zz; acc[1][1] = zz;
    mat_mm<3, false, true>(dst, dst, acc, wi, wj, g, m);
  }

  // 10. store result (fp32)
  float* ob = out + (size_t)bid * 4096;
#pragma unroll
  for (int a = 0; a < 2; a++)
#pragma unroll
    for (int b = 0; b < 2; b++)
#pragma unroll
      for (int i = 0; i < 4; i++) {
        const int row = (((wi << 1) + a) << 4) + (g << 2) + i;
        const int col = (((wj << 1) + b) << 4) + m;
        ob[row * 64 + col] = acc[a][b][i];
      }
}

extern "C" void kernel_launch(void* const* d_in, const int* in_sizes, int n_in,
                              void* d_out, int out_size, void* d_ws, size_t ws_size,
                              hipStream_t stream) {
  const float* x = (const float*)d_in[0];
  const float* W = (const float*)d_in[1];
  const float* bias = (const float*)d_in[2];
  float* out = (float*)d_out;
  float* v = (float*)d_ws;

  dim3 g1((KKc + BN - 1) / BN, BB / BM);
  gemm_silu_kernel<<<g1, dim3(256), 0, stream>>>(x, W, bias, v);
  expm_kernel<<<dim3(BB), dim3(256), 0, stream>>>(v, out);
}

// Round 4
// 401.639 us; speedup vs baseline: 2.8646x; 1.8473x over previous
//
#include <hip/hip_runtime.h>
#include <math.h>

#define BB 8192
#define NF 1024
#define KKc 2016
#define DD 64

typedef unsigned short u16;
typedef __attribute__((ext_vector_type(4))) float f32x4;
typedef __attribute__((ext_vector_type(4))) unsigned int u32x4;
typedef __attribute__((ext_vector_type(8))) short s16x8;

__device__ __forceinline__ u16 bf16_rne(float f) {
  unsigned u = __float_as_uint(f);
  return (u16)((u + 0x7fffu + ((u >> 16) & 1u)) >> 16);
}

// ---------------- Prepass A: xh/xl = split(silu(x)) ----------------
__global__ __launch_bounds__(256)
void silu_split_kernel(const float* __restrict__ x, u16* __restrict__ xh, u16* __restrict__ xl) {
  const int idx = blockIdx.x * 256 + threadIdx.x;      // float4 groups, 8192*1024/4 total
  float4 vv = ((const float4*)x)[idx];
  float a[4] = {vv.x, vv.y, vv.z, vv.w};
  u16 h[4], lo[4];
#pragma unroll
  for (int i = 0; i < 4; i++) {
    const float s = a[i] / (1.f + __expf(-a[i]));
    const u16 hh = bf16_rne(s);
    h[i] = hh;
    lo[i] = bf16_rne(s - __uint_as_float(((unsigned)hh) << 16));
  }
  ((ushort4*)xh)[idx] = make_ushort4(h[0], h[1], h[2], h[3]);
  ((ushort4*)xl)[idx] = make_ushort4(lo[0], lo[1], lo[2], lo[3]);
}

// ---------------- Prepass B: wh/wl = split(W), padded to 2048 rows ----------------
__global__ __launch_bounds__(256)
void wsplit_kernel(const float* __restrict__ W, u16* __restrict__ wh, u16* __restrict__ wl) {
  const int idx = blockIdx.x * 256 + threadIdx.x;      // float4 groups over 2048*1024
  const int row = idx >> 8;
  float4 vv = make_float4(0.f, 0.f, 0.f, 0.f);
  if (row < KKc) vv = ((const float4*)W)[idx];
  float a[4] = {vv.x, vv.y, vv.z, vv.w};
  u16 h[4], lo[4];
#pragma unroll
  for (int i = 0; i < 4; i++) {
    const u16 hh = bf16_rne(a[i]);
    h[i] = hh;
    lo[i] = bf16_rne(a[i] - __uint_as_float(((unsigned)hh) << 16));
  }
  ((ushort4*)wh)[idx] = make_ushort4(h[0], h[1], h[2], h[3]);
  ((ushort4*)wl)[idx] = make_ushort4(lo[0], lo[1], lo[2], lo[3]);
}

// ---------------- Kernel 1: v = silu(x)@W^T + b via split-bf16 MFMA ----------------
typedef __attribute__((address_space(1))) const unsigned int gu32;
typedef __attribute__((address_space(3))) unsigned int lu32;

__device__ __forceinline__ void gload_lds16(const void* g, void* l) {
  __builtin_amdgcn_global_load_lds((gu32*)g, (lu32*)l, 16, 0, 0);
}

// read 16B fragment (8 bf16, k-contiguous) for row `row`, k-chunk `kc` from swizzled tile
__device__ __forceinline__ s16x8 frag_row(const u16* T, int row, int kc) {
  const int c = kc ^ ((row >> 1) & 3);
  return *(const s16x8*)(T + row * 32 + c * 8);
}

__global__ __launch_bounds__(256, 3)
void gemm_mfma_kernel(const u16* __restrict__ xh, const u16* __restrict__ xl,
                      const u16* __restrict__ wh, const u16* __restrict__ wl,
                      const float* __restrict__ bias, float* __restrict__ v) {
  __shared__ __align__(16) u16 Ah[128 * 32];
  __shared__ __align__(16) u16 Al[128 * 32];
  __shared__ __align__(16) u16 Bh[128 * 32];
  __shared__ __align__(16) u16 Bl[128 * 32];
  const int tid = threadIdx.x;
  const int l = tid & 63, w = tid >> 6;
  const int wi = w >> 1, wj = w & 1;
  const int m0 = blockIdx.y * 128;
  const int n0 = blockIdx.x * 128;
  const int kc = l >> 4, lr = l & 15;

  // wave w stages tile w (ternary chains: no LDS-pointer arrays — addrspacecast
  // static-initializer is a compile error on gfx950)
  const int row0 = (w < 2) ? m0 : n0;
  const u16* P = (w == 0) ? xh : (w == 1) ? xl : (w == 2) ? wh : wl;
  u16* T = (w == 0) ? Ah : (w == 1) ? Al : (w == 2) ? Bh : Bl;

  f32x4 acc[4][4];
  const f32x4 zz = {0.f, 0.f, 0.f, 0.f};
#pragma unroll
  for (int a = 0; a < 4; a++)
#pragma unroll
    for (int b = 0; b < 4; b++) acc[a][b] = zz;

  for (int k0 = 0; k0 < NF; k0 += 32) {
    // stage: 8 x global_load_lds (16B/lane), source pre-swizzled so LDS is chunk^((r>>1)&3)
#pragma unroll
    for (int c8 = 0; c8 < 8; c8++) {
      const int slot = c8 * 64 + l;
      const int r = slot >> 2;
      const int c = (slot & 3) ^ ((r >> 1) & 3);
      gload_lds16(P + (size_t)(row0 + r) * NF + k0 + c * 8, T + c8 * 512);
    }
    __syncthreads();   // drains vmcnt -> tiles ready

    s16x8 fah[4], fal[4];
#pragma unroll
    for (int a = 0; a < 4; a++) {
      const int ra = wi * 64 + a * 16 + lr;
      fah[a] = frag_row(Ah, ra, kc);
      fal[a] = frag_row(Al, ra, kc);
    }
#pragma unroll
    for (int b = 0; b < 4; b++) {
      const int rb = wj * 64 + b * 16 + lr;
      const s16x8 fbh = frag_row(Bh, rb, kc);
      const s16x8 fbl = frag_row(Bl, rb, kc);
#pragma unroll
      for (int a = 0; a < 4; a++) {
        acc[a][b] = __builtin_amdgcn_mfma_f32_16x16x32_bf16(fah[a], fbh, acc[a][b], 0, 0, 0);
        acc[a][b] = __builtin_amdgcn_mfma_f32_16x16x32_bf16(fah[a], fbl, acc[a][b], 0, 0, 0);
        acc[a][b] = __builtin_amdgcn_mfma_f32_16x16x32_bf16(fal[a], fbh, acc[a][b], 0, 0, 0);
      }
    }
    __syncthreads();   // before next stage overwrites tiles
  }

  // epilogue: bias + store v (C/D: col = lane&15, row = (lane>>4)*4 + reg)
  const int grp = l >> 4;
#pragma unroll
  for (int b = 0; b < 4; b++) {
    const int n = n0 + wj * 64 + b * 16 + lr;
    if (n < KKc) {
      const float bb = bias[n];
#pragma unroll
      for (int a = 0; a < 4; a++) {
        const int mbase = m0 + wi * 64 + a * 16 + grp * 4;
#pragma unroll
        for (int i = 0; i < 4; i++)
          v[(size_t)(mbase + i) * KKc + n] = acc[a][b][i] + bb;
      }
    }
  }
}

// ---------------- Fallback fp32 GEMM (if ws too small) ----------------
#define BM 128
#define BN 128
#define BKr 16
#define XST 132

__global__ __launch_bounds__(256, 2)
void gemm_silu_kernel(const float* __restrict__ x, const float* __restrict__ W,
                      const float* __restrict__ bias, float* __restrict__ v) {
  __shared__ float xs[BKr * XST];
  __shared__ float wl[BKr * XST];
  const int tid = threadIdx.x;
  const int tx = tid & 15, ty = tid >> 4;
  const int c0g = blockIdx.x * BN;
  const int m0 = blockIdx.y * BM;
  const int lrow = tid >> 2;
  const int lu = (tid & 3) << 2;

  float acc[2][2][4][4];
#pragma unroll
  for (int a = 0; a < 2; a++)
#pragma unroll
    for (int b = 0; b < 2; b++)
#pragma unroll
      for (int i = 0; i < 4; i++)
#pragma unroll
        for (int j = 0; j < 4; j++) acc[a][b][i][j] = 0.f;

  for (int n0 = 0; n0 < NF; n0 += BKr) {
#pragma unroll
    for (int p = 0; p < 2; p++) {
      const int row = lrow + 64 * p;
      float4 xv = *(const float4*)(x + (size_t)(m0 + row) * NF + n0 + lu);
      float xa[4] = {xv.x, xv.y, xv.z, xv.w};
#pragma unroll
      for (int u = 0; u < 4; u++) {
        const float val = xa[u];
        xs[(lu + u) * XST + row] = val / (1.f + __expf(-val));
      }
      const int wr = c0g + row;
      float4 wv = make_float4(0.f, 0.f, 0.f, 0.f);
      if (wr < KKc) wv = *(const float4*)(W + (size_t)wr * NF + n0 + lu);
      float wa[4] = {wv.x, wv.y, wv.z, wv.w};
#pragma unroll
      for (int u = 0; u < 4; u++) wl[(lu + u) * XST + row] = wa[u];
    }
    __syncthreads();
#pragma unroll
    for (int k0 = 0; k0 < BKr; k0 += 4) {
#pragma unroll
      for (int kk = 0; kk < 4; kk++) {
        const float* xr = xs + (k0 + kk) * XST;
        const float* wr_ = wl + (k0 + kk) * XST;
        float4 t;
        t = *(const float4*)(xr + 4 * ty);       float a0[4] = {t.x, t.y, t.z, t.w};
        t = *(const float4*)(xr + 64 + 4 * ty);  float a1[4] = {t.x, t.y, t.z, t.w};
        t = *(const float4*)(wr_ + 4 * tx);      float b0[4] = {t.x, t.y, t.z, t.w};
        t = *(const float4*)(wr_ + 64 + 4 * tx); float b1[4] = {t.x, t.y, t.z, t.w};
#pragma unroll
        for (int i = 0; i < 4; i++)
#pragma unroll
          for (int j = 0; j < 4; j++) {
            acc[0][0][i][j] = fmaf(a0[i], b0[j], acc[0][0][i][j]);
            acc[0][1][i][j] = fmaf(a0[i], b1[j], acc[0][1][i][j]);
            acc[1][0][i][j] = fmaf(a1[i], b0[j], acc[1][0][i][j]);
            acc[1][1][i][j] = fmaf(a1[i], b1[j], acc[1][1][i][j]);
          }
      }
    }
    __syncthreads();
  }
#pragma unroll
  for (int rb = 0; rb < 2; rb++)
#pragma unroll
    for (int ii = 0; ii < 4; ii++) {
      const int row = m0 + rb * 64 + 4 * ty + ii;
#pragma unroll
      for (int cb = 0; cb < 2; cb++) {
        const int c = c0g + cb * 64 + 4 * tx;
        if (c < KKc) {
          float4 bb = *(const float4*)(bias + c);
          float4 o;
          o.x = acc[rb][cb][ii][0] + bb.x;
          o.y = acc[rb][cb][ii][1] + bb.y;
          o.z = acc[rb][cb][ii][2] + bb.z;
          o.w = acc[rb][cb][ii][3] + bb.w;
          *(float4*)(v + (size_t)row * KKc + c) = o;
        }
      }
    }
}

// ---------------- Kernel 2: R = expm(skew(v_row)) via split-bf16 MFMA ----------------
union FragU { u32x4 u; s16x8 s; };

__device__ __forceinline__ int daddr(int row, int col) {
  return (row << 6) | ((((col >> 2) ^ (row & 15)) << 2) | (col & 3));
}

__device__ __forceinline__ unsigned pack_split(float v) {
  unsigned uv = __float_as_uint(v);
  unsigned hi16 = (uv + 0x7fffu + ((uv >> 16) & 1u)) >> 16;
  float fhi = __uint_as_float(hi16 << 16);
  float lo = v - fhi;
  unsigned ul = __float_as_uint(lo);
  unsigned lo16 = (ul + 0x7fffu + ((ul >> 16) & 1u)) >> 16;
  return hi16 | (lo16 << 16);
}

__device__ __forceinline__ void load_rowfrag(const unsigned* P, int row, int kb, int g,
                                             FragU& fh, FragU& fl, bool neg) {
  const int sw = row & 15;
  const int q0 = (kb << 3) + (g << 1);
  const unsigned* base = P + (row << 6);
  u32x4 A0 = *(const u32x4*)(base + ((q0 ^ sw) << 2));
  u32x4 A1 = *(const u32x4*)(base + (((q0 + 1) ^ sw) << 2));
  unsigned u[8] = {A0[0], A0[1], A0[2], A0[3], A1[0], A1[1], A1[2], A1[3]};
  const unsigned xm = neg ? 0x80008000u : 0u;
#pragma unroll
  for (int r = 0; r < 4; r++) {
    fh.u[r] = (((u[2 * r] & 0xffffu) | (u[2 * r + 1] << 16)) ^ xm);
    fl.u[r] = (((u[2 * r] >> 16) | (u[2 * r + 1] & 0xffff0000u)) ^ xm);
  }
}

__device__ __forceinline__ void load_colfrag(const unsigned* P, int n, int kb, int g,
                                             FragU& fh, FragU& fl) {
  const int kbase = (kb << 5) + (g << 3);
  const int nq = n >> 2, ne = n & 3;
  unsigned u[8];
#pragma unroll
  for (int e = 0; e < 8; e++) {
    const int k = kbase + e;
    u[e] = P[(k << 6) | (((nq ^ (k & 15)) << 2) | ne)];
  }
#pragma unroll
  for (int r = 0; r < 4; r++) {
    fh.u[r] = ((u[2 * r] & 0xffffu) | (u[2 * r + 1] << 16));
    fl.u[r] = ((u[2 * r] >> 16) | (u[2 * r + 1] & 0xffff0000u));
  }
}

template<int NPASS, bool NEGB, bool COLB>
__device__ __forceinline__ void mat_mm(const unsigned* Ab, const unsigned* Bb,
                                       f32x4 acc[2][2], int wi, int wj, int g, int m) {
#pragma unroll
  for (int kb = 0; kb < 2; kb++) {
    FragU bh[2], bl[2];
#pragma unroll
    for (int b = 0; b < 2; b++) {
      const int n = ((((wj << 1) + b) << 4) | m);
      if (COLB) load_colfrag(Bb, n, kb, g, bh[b], bl[b]);
      else      load_rowfrag(Bb, n, kb, g, bh[b], bl[b], NEGB);
    }
#pragma unroll
    for (int a = 0; a < 2; a++) {
      FragU ah, al;
      const int row = ((((wi << 1) + a) << 4) | m);
      load_rowfrag(Ab, row, kb, g, ah, al, false);
#pragma unroll
      for (int b = 0; b < 2; b++) {
        acc[a][b] = __builtin_amdgcn_mfma_f32_16x16x32_bf16(ah.s, bh[b].s, acc[a][b], 0, 0, 0);
        if (NPASS == 3) {
          acc[a][b] = __builtin_amdgcn_mfma_f32_16x16x32_bf16(ah.s, bl[b].s, acc[a][b], 0, 0, 0);
          acc[a][b] = __builtin_amdgcn_mfma_f32_16x16x32_bf16(al.s, bh[b].s, acc[a][b], 0, 0, 0);
        }
      }
    }
  }
}

__device__ __forceinline__ void pack_write(unsigned* P, const f32x4 v[2][2],
                                           int wi, int wj, int g, int m) {
#pragma unroll
  for (int a = 0; a < 2; a++)
#pragma unroll
    for (int b = 0; b < 2; b++)
#pragma unroll
      for (int i = 0; i < 4; i++) {
        const int row = (((wi << 1) + a) << 4) + (g << 2) + i;
        const int col = (((wj << 1) + b) << 4) + m;
        P[daddr(row, col)] = pack_split(v[a][b][i]);
      }
}

__global__ __launch_bounds__(256, 3)
void expm_kernel(const float* __restrict__ v, float* __restrict__ out) {
  __shared__ __align__(16) unsigned B0s[4096];
  __shared__ __align__(16) unsigned B1s[4096];
  __shared__ __align__(16) unsigned B2s[4096];
  __shared__ float red[4];
  const int tid = threadIdx.x;
  const int bid = blockIdx.x;
  const int l = tid & 63, w = tid >> 6;
  const int g = l >> 4, m = l & 15;
  const int wi = w >> 1, wj = w & 1;

  {
    float* vbw = (float*)B2s;
    const float* vr = v + (size_t)bid * KKc;
#pragma unroll
    for (int it = 0; it < 8; it++) {
      const int idx = tid + 256 * it;
      if (idx < KKc) vbw[idx] = vr[idx];
    }
  }
  __syncthreads();

  float vals[16];
  float fs = 0.f;
  {
    const float* vb = (const float*)B2s;
#pragma unroll
    for (int rr = 0; rr < 16; rr++) {
      const int row = rr * 4 + w;
      const int col = l;
      float val = 0.f;
      if (row < col)      val =  vb[(row * (127 - row)) / 2 + col - row - 1];
      else if (row > col) val = -vb[(col * (127 - col)) / 2 + row - col - 1];
      vals[rr] = val;
      fs += val * val;
    }
  }
#pragma unroll
  for (int k = 1; k < 64; k <<= 1) fs += __shfl_xor(fs, k, 64);
  if (l == 0) red[w] = fs;
  __syncthreads();
  const float nf = sqrtf(red[0] + red[1] + red[2] + red[3]);
  int s = 0;
  if (nf > 1.f) { s = (int)ceilf(log2f(nf)); if (s > 30) s = 30; if (s < 0) s = 0; }
  const float sc = exp2f(-(float)s);
  __syncthreads();

#pragma unroll
  for (int rr = 0; rr < 16; rr++) {
    const int row = rr * 4 + w;
    B0s[daddr(row, l)] = pack_split(vals[rr] * sc);
  }
  __syncthreads();

  const f32x4 zz = {0.f, 0.f, 0.f, 0.f};
  f32x4 acc[2][2];

  acc[0][0] = zz; acc[0][1] = zz; acc[1][0] = zz; acc[1][1] = zz;
  mat_mm<3, true, false>(B0s, B0s, acc, wi, wj, g, m);
  f32x4 rX2[2][2];
  rX2[0][0] = acc[0][0]; rX2[0][1] = acc[0][1]; rX2[1][0] = acc[1][0]; rX2[1][1] = acc[1][1];
  pack_write(B1s, acc, wi, wj, g, m);
  __syncthreads();

  acc[0][0] = zz; acc[0][1] = zz; acc[1][0] = zz; acc[1][1] = zz;
  mat_mm<3, false, false>(B1s, B1s, acc, wi, wj, g, m);
  f32x4 rEp[2][2], rS3[2][2];
#pragma unroll
  for (int a = 0; a < 2; a++)
#pragma unroll
    for (int b = 0; b < 2; b++)
#pragma unroll
      for (int i = 0; i < 4; i++) {
        const int row = (((wi << 1) + a) << 4) + (g << 2) + i;
        const int col = (((wj << 1) + b) << 4) + m;
        const float dg = (row == col) ? 1.f : 0.f;
        const float x2 = rX2[a][b][i], x4 = acc[a][b][i];
        rEp[a][b][i] = dg + 0.5f * x2 + (1.f / 24.f) * x4;
        rS3[a][b][i] = dg + (1.f / 6.f) * x2 + (1.f / 120.f) * x4;
      }
  pack_write(B2s, acc, wi, wj, g, m);
  __syncthreads();

  acc[0][0] = zz; acc[0][1] = zz; acc[1][0] = zz; acc[1][1] = zz;
  mat_mm<1, false, false>(B2s, B1s, acc, wi, wj, g, m);
#pragma unroll
  for (int a = 0; a < 2; a++)
#pragma unroll
    for (int b = 0; b < 2; b++)
#pragma unroll
      for (int i = 0; i < 4; i++) {
        rEp[a][b][i] += (1.f / 720.f) * acc[a][b][i];
        rS3[a][b][i] += (1.f / 5040.f) * acc[a][b][i];
      }

  acc[0][0] = zz; acc[0][1] = zz; acc[1][0] = zz; acc[1][1] = zz;
  mat_mm<1, false, false>(B2s, B2s, acc, wi, wj, g, m);
#pragma unroll
  for (int a = 0; a < 2; a++)
#pragma unroll
    for (int b = 0; b < 2; b++)
#pragma unroll
      for (int i = 0; i < 4; i++)
        rEp[a][b][i] += (1.f / 40320.f) * acc[a][b][i];
  __syncthreads();
  pack_write(B2s, rS3, wi, wj, g, m);
  __syncthreads();

  acc[0][0] = rEp[0][0]; acc[0][1] = rEp[0][1]; acc[1][0] = rEp[1][0]; acc[1][1] = rEp[1][1];
  mat_mm<3, false, false>(B0s, B2s, acc, wi, wj, g, m);

  for (int t = 0; t < s; t++) {
    unsigned* dst = (t & 1) ? B2s : B1s;
    pack_write(dst, acc, wi, wj, g, m);
    __syncthreads();
    acc[0][0] = zz; acc[0][1] = zz; acc[1][0] = zz; acc[1][1] = zz;
    mat_mm<3, false, true>(dst, dst, acc, wi, wj, g, m);
  }

  float* ob = out + (size_t)bid * 4096;
#pragma unroll
  for (int a = 0; a < 2; a++)
#pragma unroll
    for (int b = 0; b < 2; b++)
#pragma unroll
      for (int i = 0; i < 4; i++) {
        const int row = (((wi << 1) + a) << 4) + (g << 2) + i;
        const int col = (((wj << 1) + b) << 4) + m;
        ob[row * 64 + col] = acc[a][b][i];
      }
}

extern "C" void kernel_launch(void* const* d_in, const int* in_sizes, int n_in,
                              void* d_out, int out_size, void* d_ws, size_t ws_size,
                              hipStream_t stream) {
  const float* x = (const float*)d_in[0];
  const float* W = (const float*)d_in[1];
  const float* bias = (const float*)d_in[2];
  float* out = (float*)d_out;
  char* ws = (char*)d_ws;
  float* v = (float*)ws;                         // 66,060,288 B

  const size_t V_BYTES  = (size_t)BB * KKc * 4;  // 66,060,288
  const size_t XH_ELEMS = (size_t)BB * NF;       // 8,388,608
  const size_t WH_ELEMS = (size_t)2048 * NF;     // 2,097,152
  const size_t NEED = V_BYTES + 2 * XH_ELEMS * 2 + 2 * WH_ELEMS * 2;

  if (ws_size >= NEED) {
    u16* xh = (u16*)(ws + V_BYTES);
    u16* xl = xh + XH_ELEMS;
    u16* wh = xl + XH_ELEMS;
    u16* wlp = wh + WH_ELEMS;
    silu_split_kernel<<<dim3(BB * NF / 4 / 256), dim3(256), 0, stream>>>(x, xh, xl);
    wsplit_kernel<<<dim3(2048 * NF / 4 / 256), dim3(256), 0, stream>>>(W, wh, wlp);
    gemm_mfma_kernel<<<dim3(16, 64), dim3(256), 0, stream>>>(xh, xl, wh, wlp, bias, v);
  } else {
    dim3 g1((KKc + BN - 1) / BN, BB / BM);
    gemm_silu_kernel<<<g1, dim3(256), 0, stream>>>(x, W, bias, v);
  }
  expm_kernel<<<dim3(BB), dim3(256), 0, stream>>>(v, out);
}

// Round 5
// 317.576 us; speedup vs baseline: 3.6229x; 1.2647x over previous
//
#include <hip/hip_runtime.h>
#include <math.h>

#define BB 8192
#define NF 1024
#define KKc 2016
#define DD 64

typedef unsigned short u16;
typedef __attribute__((ext_vector_type(4))) float f32x4;
typedef __attribute__((ext_vector_type(4))) unsigned int u32x4;
typedef __attribute__((ext_vector_type(8))) short s16x8;
typedef __attribute__((ext_vector_type(8))) unsigned short u16x8;

__device__ __forceinline__ u16 bf16_rne(float f) {
  unsigned u = __float_as_uint(f);
  return (u16)((u + 0x7fffu + ((u >> 16) & 1u)) >> 16);
}

// ---------------- Prepass A: xh/xl = split(silu(x)) ----------------
__global__ __launch_bounds__(256)
void silu_split_kernel(const float* __restrict__ x, u16* __restrict__ xh, u16* __restrict__ xl) {
  const int idx = blockIdx.x * 256 + threadIdx.x;
  float4 vv = ((const float4*)x)[idx];
  float a[4] = {vv.x, vv.y, vv.z, vv.w};
  u16 h[4], lo[4];
#pragma unroll
  for (int i = 0; i < 4; i++) {
    const float s = a[i] / (1.f + __expf(-a[i]));
    const u16 hh = bf16_rne(s);
    h[i] = hh;
    lo[i] = bf16_rne(s - __uint_as_float(((unsigned)hh) << 16));
  }
  ((ushort4*)xh)[idx] = make_ushort4(h[0], h[1], h[2], h[3]);
  ((ushort4*)xl)[idx] = make_ushort4(lo[0], lo[1], lo[2], lo[3]);
}

// ---------------- Prepass B: wh/wl = split(W), padded to 2048 rows ----------------
__global__ __launch_bounds__(256)
void wsplit_kernel(const float* __restrict__ W, u16* __restrict__ wh, u16* __restrict__ wl) {
  const int idx = blockIdx.x * 256 + threadIdx.x;
  const int row = idx >> 8;
  float4 vv = make_float4(0.f, 0.f, 0.f, 0.f);
  if (row < KKc) vv = ((const float4*)W)[idx];
  float a[4] = {vv.x, vv.y, vv.z, vv.w};
  u16 h[4], lo[4];
#pragma unroll
  for (int i = 0; i < 4; i++) {
    const u16 hh = bf16_rne(a[i]);
    h[i] = hh;
    lo[i] = bf16_rne(a[i] - __uint_as_float(((unsigned)hh) << 16));
  }
  ((ushort4*)wh)[idx] = make_ushort4(h[0], h[1], h[2], h[3]);
  ((ushort4*)wl)[idx] = make_ushort4(lo[0], lo[1], lo[2], lo[3]);
}

// ---------------- Kernel 1: v = silu(x)@W^T + b via split-bf16 MFMA ----------------
typedef __attribute__((address_space(1))) const unsigned int gu32;
typedef __attribute__((address_space(3))) unsigned int lu32;

__device__ __forceinline__ void gload_lds16(const void* g, void* l) {
  __builtin_amdgcn_global_load_lds((gu32*)g, (lu32*)l, 16, 0, 0);
}

__device__ __forceinline__ s16x8 frag_row32(const u16* T, int row, int kc) {
  const int c = kc ^ ((row >> 1) & 3);
  return *(const s16x8*)(T + row * 32 + c * 8);
}

__global__ __launch_bounds__(256, 3)
void gemm_mfma_kernel(const u16* __restrict__ xh, const u16* __restrict__ xl,
                      const u16* __restrict__ wh, const u16* __restrict__ wl,
                      const float* __restrict__ bias, float* __restrict__ v) {
  __shared__ __align__(16) u16 Ah[128 * 32];
  __shared__ __align__(16) u16 Al[128 * 32];
  __shared__ __align__(16) u16 Bh[128 * 32];
  __shared__ __align__(16) u16 Bl[128 * 32];
  const int tid = threadIdx.x;
  const int l = tid & 63, w = tid >> 6;
  const int wi = w >> 1, wj = w & 1;
  const int m0 = blockIdx.y * 128;
  const int n0 = blockIdx.x * 128;
  const int kc = l >> 4, lr = l & 15;

  const int row0 = (w < 2) ? m0 : n0;
  const u16* P = (w == 0) ? xh : (w == 1) ? xl : (w == 2) ? wh : wl;
  u16* T = (w == 0) ? Ah : (w == 1) ? Al : (w == 2) ? Bh : Bl;

  f32x4 acc[4][4];
  const f32x4 zz = {0.f, 0.f, 0.f, 0.f};
#pragma unroll
  for (int a = 0; a < 4; a++)
#pragma unroll
    for (int b = 0; b < 4; b++) acc[a][b] = zz;

  for (int k0 = 0; k0 < NF; k0 += 32) {
#pragma unroll
    for (int c8 = 0; c8 < 8; c8++) {
      const int slot = c8 * 64 + l;
      const int r = slot >> 2;
      const int c = (slot & 3) ^ ((r >> 1) & 3);
      gload_lds16(P + (size_t)(row0 + r) * NF + k0 + c * 8, T + c8 * 512);
    }
    __syncthreads();

    s16x8 fah[4], fal[4];
#pragma unroll
    for (int a = 0; a < 4; a++) {
      const int ra = wi * 64 + a * 16 + lr;
      fah[a] = frag_row32(Ah, ra, kc);
      fal[a] = frag_row32(Al, ra, kc);
    }
#pragma unroll
    for (int b = 0; b < 4; b++) {
      const int rb = wj * 64 + b * 16 + lr;
      const s16x8 fbh = frag_row32(Bh, rb, kc);
      const s16x8 fbl = frag_row32(Bl, rb, kc);
#pragma unroll
      for (int a = 0; a < 4; a++) {
        acc[a][b] = __builtin_amdgcn_mfma_f32_16x16x32_bf16(fah[a], fbh, acc[a][b], 0, 0, 0);
        acc[a][b] = __builtin_amdgcn_mfma_f32_16x16x32_bf16(fah[a], fbl, acc[a][b], 0, 0, 0);
        acc[a][b] = __builtin_amdgcn_mfma_f32_16x16x32_bf16(fal[a], fbh, acc[a][b], 0, 0, 0);
      }
    }
    __syncthreads();
  }

  const int grp = l >> 4;
#pragma unroll
  for (int b = 0; b < 4; b++) {
    const int n = n0 + wj * 64 + b * 16 + lr;
    if (n < KKc) {
      const float bb = bias[n];
#pragma unroll
      for (int a = 0; a < 4; a++) {
        const int mbase = m0 + wi * 64 + a * 16 + grp * 4;
#pragma unroll
        for (int i = 0; i < 4; i++)
          v[(size_t)(mbase + i) * KKc + n] = acc[a][b][i] + bb;
      }
    }
  }
}

// ---------------- Fallback fp32 GEMM (if ws too small) ----------------
#define BM 128
#define BN 128
#define BKr 16
#define XST 132

__global__ __launch_bounds__(256, 2)
void gemm_silu_kernel(const float* __restrict__ x, const float* __restrict__ W,
                      const float* __restrict__ bias, float* __restrict__ v) {
  __shared__ float xs[BKr * XST];
  __shared__ float wl[BKr * XST];
  const int tid = threadIdx.x;
  const int tx = tid & 15, ty = tid >> 4;
  const int c0g = blockIdx.x * BN;
  const int m0 = blockIdx.y * BM;
  const int lrow = tid >> 2;
  const int lu = (tid & 3) << 2;

  float acc[2][2][4][4];
#pragma unroll
  for (int a = 0; a < 2; a++)
#pragma unroll
    for (int b = 0; b < 2; b++)
#pragma unroll
      for (int i = 0; i < 4; i++)
#pragma unroll
        for (int j = 0; j < 4; j++) acc[a][b][i][j] = 0.f;

  for (int n0 = 0; n0 < NF; n0 += BKr) {
#pragma unroll
    for (int p = 0; p < 2; p++) {
      const int row = lrow + 64 * p;
      float4 xv = *(const float4*)(x + (size_t)(m0 + row) * NF + n0 + lu);
      float xa[4] = {xv.x, xv.y, xv.z, xv.w};
#pragma unroll
      for (int u = 0; u < 4; u++) {
        const float val = xa[u];
        xs[(lu + u) * XST + row] = val / (1.f + __expf(-val));
      }
      const int wr = c0g + row;
      float4 wv = make_float4(0.f, 0.f, 0.f, 0.f);
      if (wr < KKc) wv = *(const float4*)(W + (size_t)wr * NF + n0 + lu);
      float wa[4] = {wv.x, wv.y, wv.z, wv.w};
#pragma unroll
      for (int u = 0; u < 4; u++) wl[(lu + u) * XST + row] = wa[u];
    }
    __syncthreads();
#pragma unroll
    for (int k0 = 0; k0 < BKr; k0 += 4) {
#pragma unroll
      for (int kk = 0; kk < 4; kk++) {
        const float* xr = xs + (k0 + kk) * XST;
        const float* wr_ = wl + (k0 + kk) * XST;
        float4 t;
        t = *(const float4*)(xr + 4 * ty);       float a0[4] = {t.x, t.y, t.z, t.w};
        t = *(const float4*)(xr + 64 + 4 * ty);  float a1[4] = {t.x, t.y, t.z, t.w};
        t = *(const float4*)(wr_ + 4 * tx);      float b0[4] = {t.x, t.y, t.z, t.w};
        t = *(const float4*)(wr_ + 64 + 4 * tx); float b1[4] = {t.x, t.y, t.z, t.w};
#pragma unroll
        for (int i = 0; i < 4; i++)
#pragma unroll
          for (int j = 0; j < 4; j++) {
            acc[0][0][i][j] = fmaf(a0[i], b0[j], acc[0][0][i][j]);
            acc[0][1][i][j] = fmaf(a0[i], b1[j], acc[0][1][i][j]);
            acc[1][0][i][j] = fmaf(a1[i], b0[j], acc[1][0][i][j]);
            acc[1][1][i][j] = fmaf(a1[i], b1[j], acc[1][1][i][j]);
          }
      }
    }
    __syncthreads();
  }
#pragma unroll
  for (int rb = 0; rb < 2; rb++)
#pragma unroll
    for (int ii = 0; ii < 4; ii++) {
      const int row = m0 + rb * 64 + 4 * ty + ii;
#pragma unroll
      for (int cb = 0; cb < 2; cb++) {
        const int c = c0g + cb * 64 + 4 * tx;
        if (c < KKc) {
          float4 bb = *(const float4*)(bias + c);
          float4 o;
          o.x = acc[rb][cb][ii][0] + bb.x;
          o.y = acc[rb][cb][ii][1] + bb.y;
          o.z = acc[rb][cb][ii][2] + bb.z;
          o.w = acc[rb][cb][ii][3] + bb.w;
          *(float4*)(v + (size_t)row * KKc + c) = o;
        }
      }
    }
}

// ---------------- Kernel 2: R = expm(skew(v_row)) — separate hi/lo bf16 planes ----------------
// LDS layout per plane: u16[64][64], 16B chunk swizzle: chunk' = chunk ^ (row&7).

union FragX { u16x8 u; s16x8 s; u32x4 d; };

__device__ __forceinline__ s16x8 fragld(const u16* P, int row, int chunk) {
  return *(const s16x8*)(P + ((row << 6) | ((chunk ^ (row & 7)) << 3)));
}

__device__ __forceinline__ s16x8 fneg(s16x8 f) {
  FragX x; x.s = f;
  x.d ^= (u32x4){0x80008000u, 0x80008000u, 0x80008000u, 0x80008000u};
  return x.s;
}

__device__ __forceinline__ void split4(const f32x4 v, ushort4& h, ushort4& l) {
  unsigned hu[4], lu[4];
#pragma unroll
  for (int i = 0; i < 4; i++) {
    const float f = v[i];
    const unsigned u = __float_as_uint(f);
    const unsigned hh = (u + 0x7fffu + ((u >> 16) & 1u)) >> 16;
    const float fl = f - __uint_as_float(hh << 16);
    const unsigned ul = __float_as_uint(fl);
    hu[i] = hh;
    lu[i] = (ul + 0x7fffu + ((ul >> 16) & 1u)) >> 16;
  }
  h = make_ushort4((u16)hu[0], (u16)hu[1], (u16)hu[2], (u16)hu[3]);
  l = make_ushort4((u16)lu[0], (u16)lu[1], (u16)lu[2], (u16)lu[3]);
}

// acc += A*B ; A-frags row-read from A-planes; B-frags row-read from B-planes
// (valid when B buffer is symmetric, a col-copy, or skew with NEGB).
template<int NPASS, bool NEGB>
__device__ __forceinline__ void mat_mm(const u16* APh, const u16* APl,
                                       const u16* BPh, const u16* BPl,
                                       f32x4 acc[2][2], int wi, int wj, int g, int lr) {
#pragma unroll
  for (int kb = 0; kb < 2; kb++) {
    const int ch = (kb << 2) | g;
    s16x8 bh[2], bl[2];
#pragma unroll
    for (int b = 0; b < 2; b++) {
      const int n = wj * 32 + b * 16 + lr;
      bh[b] = fragld(BPh, n, ch);
      if (NEGB) bh[b] = fneg(bh[b]);
      if (NPASS == 3) {
        bl[b] = fragld(BPl, n, ch);
        if (NEGB) bl[b] = fneg(bl[b]);
      }
    }
#pragma unroll
    for (int a = 0; a < 2; a++) {
      const int r = wi * 32 + a * 16 + lr;
      const s16x8 ah = fragld(APh, r, ch);
      s16x8 al;
      if (NPASS == 3) al = fragld(APl, r, ch);
#pragma unroll
      for (int b = 0; b < 2; b++) {
        acc[a][b] = __builtin_amdgcn_mfma_f32_16x16x32_bf16(ah, bh[b], acc[a][b], 0, 0, 0);
        if (NPASS == 3) {
          acc[a][b] = __builtin_amdgcn_mfma_f32_16x16x32_bf16(ah, bl[b], acc[a][b], 0, 0, 0);
          acc[a][b] = __builtin_amdgcn_mfma_f32_16x16x32_bf16(al, bh[b], acc[a][b], 0, 0, 0);
        }
      }
    }
  }
}

// write acc as [col][row] copy (b64 contiguous). For SYMMETRIC matrices this IS the
// row-major layout.
__device__ __forceinline__ void pack_col(u16* Ch, u16* Cl, const f32x4 acc[2][2],
                                         int wi, int wj, int g, int lr) {
#pragma unroll
  for (int a = 0; a < 2; a++) {
    const int r0 = wi * 32 + a * 16 + g * 4;
#pragma unroll
    for (int b = 0; b < 2; b++) {
      const int c = wj * 32 + b * 16 + lr;
      ushort4 h, l;
      split4(acc[a][b], h, l);
      const int ad = (c << 6) | (((((r0 >> 3)) ^ (c & 7)) << 3) | (r0 & 7));
      *(ushort4*)(Ch + ad) = h;
      *(ushort4*)(Cl + ad) = l;
    }
  }
}

// write acc to BOTH row-major copy (scalar b16) and col-major copy (b64) — squaring chain
__device__ __forceinline__ void pack_dual(u16* Rh, u16* Rl, u16* Ch, u16* Cl,
                                          const f32x4 acc[2][2], int wi, int wj, int g, int lr) {
#pragma unroll
  for (int a = 0; a < 2; a++) {
    const int r0 = wi * 32 + a * 16 + g * 4;
#pragma unroll
    for (int b = 0; b < 2; b++) {
      const int c = wj * 32 + b * 16 + lr;
      ushort4 h, l;
      split4(acc[a][b], h, l);
      const int adc = (c << 6) | (((((r0 >> 3)) ^ (c & 7)) << 3) | (r0 & 7));
      *(ushort4*)(Ch + adc) = h;
      *(ushort4*)(Cl + adc) = l;
      const u16 ha[4] = {h.x, h.y, h.z, h.w};
      const u16 la[4] = {l.x, l.y, l.z, l.w};
#pragma unroll
      for (int i = 0; i < 4; i++) {
        const int r = r0 + i;
        const int adr = (r << 6) | ((((c >> 3) ^ (r & 7)) << 3) | (c & 7));
        Rh[adr] = ha[i];
        Rl[adr] = la[i];
      }
    }
  }
}

__global__ __launch_bounds__(256, 3)
void expm_kernel(const float* __restrict__ v, float* __restrict__ out) {
  __shared__ __align__(16) u16 Ahs[4096], Als[4096];
  __shared__ __align__(16) u16 P1h[4096], P1l[4096];
  __shared__ __align__(16) u16 P2h[4096], P2l[4096];
  __shared__ float red[4];
  const int tid = threadIdx.x;
  const int bid = blockIdx.x;
  const int l = tid & 63, w = tid >> 6;
  const int g = l >> 4, lr = l & 15;
  const int wi = w >> 1, wj = w & 1;

  // 1. stage v row into P2h (as floats; 2016*4B = 8064 <= 8192)
  {
    float* vb = (float*)P2h;
    const float* vr = v + (size_t)bid * KKc;
    for (int i = tid; i < KKc; i += 256) vb[i] = vr[i];
  }
  __syncthreads();

  // 2. build skew A (UNSCALED) into Ah/Al planes. thread: row=tid>>2, cols 16q..16q+15
  {
    const float* vb = (const float*)P2h;
    const int arow = tid >> 2, q = tid & 3;
    u16 hh[16], ll[16];
#pragma unroll
    for (int j = 0; j < 16; j++) {
      const int c = q * 16 + j;
      float val = 0.f;
      if (arow < c)      val =  vb[(arow * (127 - arow)) / 2 + c - arow - 1];
      else if (arow > c) val = -vb[(c * (127 - c)) / 2 + arow - c - 1];
      const u16 hv = bf16_rne(val);
      hh[j] = hv;
      ll[j] = bf16_rne(val - __uint_as_float(((unsigned)hv) << 16));
    }
    __syncthreads();   // all reads of vb done before any plane write aliases (safety)
#pragma unroll
    for (int cc = 0; cc < 2; cc++) {
      const int ch = 2 * q + cc;
      const int ad = (arow << 6) | ((ch ^ (arow & 7)) << 3);
      u16x8 vh, vl;
#pragma unroll
      for (int e = 0; e < 8; e++) { vh[e] = hh[cc * 8 + e]; vl[e] = ll[cc * 8 + e]; }
      *(u16x8*)(Ahs + ad) = vh;
      *(u16x8*)(Als + ad) = vl;
    }
  }
  __syncthreads();

  const f32x4 zz = {0.f, 0.f, 0.f, 0.f};
  f32x4 acc[2][2];

  // 3. A2 = A*A (unscaled; B-frag = -(row-read of skew A))
  acc[0][0] = zz; acc[0][1] = zz; acc[1][0] = zz; acc[1][1] = zz;
  mat_mm<3, true>(Ahs, Als, Ahs, Als, acc, wi, wj, g, lr);
  f32x4 rA2[2][2];
  rA2[0][0] = acc[0][0]; rA2[0][1] = acc[0][1]; rA2[1][0] = acc[1][0]; rA2[1][1] = acc[1][1];
  pack_col(P1h, P1l, acc, wi, wj, g, lr);   // A2 symmetric -> col-copy == row-major
  __syncthreads();

  // 4. A4 = A2*A2 ; norm reduce for s
  acc[0][0] = zz; acc[0][1] = zz; acc[1][0] = zz; acc[1][1] = zz;
  mat_mm<3, false>(P1h, P1l, P1h, P1l, acc, wi, wj, g, lr);
  pack_col(P2h, P2l, acc, wi, wj, g, lr);   // A4 symmetric (v-staging dead)
  {
    float fs = 0.f;
#pragma unroll
    for (int a = 0; a < 2; a++)
#pragma unroll
      for (int b = 0; b < 2; b++)
#pragma unroll
        for (int i = 0; i < 4; i++) fs = fmaf(acc[a][b][i], acc[a][b][i], fs);
#pragma unroll
    for (int k = 1; k < 64; k <<= 1) fs += __shfl_xor(fs, k, 64);
    if (l == 0) red[w] = fs;
  }
  __syncthreads();

  // s: lambda_max <= ||A^4||_F^{1/4} = nf8^{1/8}  (skew => normal matrix)
  const float nf8 = red[0] + red[1] + red[2] + red[3];
  int s = 0;
  if (nf8 > 1.f) {
    s = (int)ceilf(0.125f * log2f(nf8));
    if (s < 0) s = 0;
    if (s > 15) s = 15;
  }
  const float t = exp2f(-(float)s);
  const float t2 = t * t, t4 = t2 * t2, t6 = t4 * t2, t8 = t4 * t4;
  const float e2 = 0.5f * t2, e4 = t4 / 24.f, e6 = t6 / 720.f, e8 = t8 / 40320.f;
  const float o1 = t, o3 = t * t2 / 6.f, o5 = t * t4 / 120.f, o7 = t * t6 / 5040.f;

  // fold E and S3' partials (X^{2k} = t^{2k} A^{2k})
  f32x4 rE[2][2], rS3[2][2];
#pragma unroll
  for (int a = 0; a < 2; a++)
#pragma unroll
    for (int b = 0; b < 2; b++)
#pragma unroll
      for (int i = 0; i < 4; i++) {
        const int row = wi * 32 + a * 16 + g * 4 + i;
        const int col = wj * 32 + b * 16 + lr;
        const float dg = (row == col) ? 1.f : 0.f;
        rE[a][b][i]  = dg + e2 * rA2[a][b][i] + e4 * acc[a][b][i];
        rS3[a][b][i] = o1 * dg + o3 * rA2[a][b][i] + o5 * acc[a][b][i];
      }

  // 5. A6 = A4*A2 (1-pass, acc-only)
  acc[0][0] = zz; acc[0][1] = zz; acc[1][0] = zz; acc[1][1] = zz;
  mat_mm<1, false>(P2h, P2l, P1h, P1l, acc, wi, wj, g, lr);
#pragma unroll
  for (int a = 0; a < 2; a++)
#pragma unroll
    for (int b = 0; b < 2; b++)
#pragma unroll
      for (int i = 0; i < 4; i++) {
        rE[a][b][i]  += e6 * acc[a][b][i];
        rS3[a][b][i] += o7 * acc[a][b][i];
      }

  // 6. A8 = A4*A4 (1-pass, acc-only)
  acc[0][0] = zz; acc[0][1] = zz; acc[1][0] = zz; acc[1][1] = zz;
  mat_mm<1, false>(P2h, P2l, P2h, P2l, acc, wi, wj, g, lr);
#pragma unroll
  for (int a = 0; a < 2; a++)
#pragma unroll
    for (int b = 0; b < 2; b++)
#pragma unroll
      for (int i = 0; i < 4; i++) rE[a][b][i] += e8 * acc[a][b][i];

  __syncthreads();                       // all reads of P1 (A2) done before S3' overwrite
  pack_col(P1h, P1l, rS3, wi, wj, g, lr);  // S3' symmetric
  __syncthreads();

  // 7. R0 = E + A * S3'   (acc init = E; S3' carries the t scale)
  acc[0][0] = rE[0][0]; acc[0][1] = rE[0][1]; acc[1][0] = rE[1][0]; acc[1][1] = rE[1][1];
  mat_mm<3, false>(Ahs, Als, P1h, P1l, acc, wi, wj, g, lr);
  __syncthreads();                       // all reads of Ah/P1 done before squaring overwrites

  // 8. s squarings, in-place dual buffers: row-copy in P2, col-copy in Ahs
  for (int it = 0; it < s; it++) {
    pack_dual(P2h, P2l, Ahs, Als, acc, wi, wj, g, lr);
    __syncthreads();
    acc[0][0] = zz; acc[0][1] = zz; acc[1][0] = zz; acc[1][1] = zz;
    mat_mm<3, false>(P2h, P2l, Ahs, Als, acc, wi, wj, g, lr);
    __syncthreads();
  }

  // 9. store result
  float* ob = out + (size_t)bid * 4096;
#pragma unroll
  for (int a = 0; a < 2; a++)
#pragma unroll
    for (int b = 0; b < 2; b++)
#pragma unroll
      for (int i = 0; i < 4; i++) {
        const int row = wi * 32 + a * 16 + g * 4 + i;
        const int col = wj * 32 + b * 16 + lr;
        ob[row * 64 + col] = acc[a][b][i];
      }
}

extern "C" void kernel_launch(void* const* d_in, const int* in_sizes, int n_in,
                              void* d_out, int out_size, void* d_ws, size_t ws_size,
                              hipStream_t stream) {
  const float* x = (const float*)d_in[0];
  const float* W = (const float*)d_in[1];
  const float* bias = (const float*)d_in[2];
  float* out = (float*)d_out;
  char* ws = (char*)d_ws;
  float* v = (float*)ws;

  const size_t V_BYTES  = (size_t)BB * KKc * 4;
  const size_t XH_ELEMS = (size_t)BB * NF;
  const size_t WH_ELEMS = (size_t)2048 * NF;
  const size_t NEED = V_BYTES + 2 * XH_ELEMS * 2 + 2 * WH_ELEMS * 2;

  if (ws_size >= NEED) {
    u16* xh = (u16*)(ws + V_BYTES);
    u16* xl = xh + XH_ELEMS;
    u16* wh = xl + XH_ELEMS;
    u16* wlp = wh + WH_ELEMS;
    silu_split_kernel<<<dim3(BB * NF / 4 / 256), dim3(256), 0, stream>>>(x, xh, xl);
    wsplit_kernel<<<dim3(2048 * NF / 4 / 256), dim3(256), 0, stream>>>(W, wh, wlp);
    gemm_mfma_kernel<<<dim3(16, 64), dim3(256), 0, stream>>>(xh, xl, wh, wlp, bias, v);
  } else {
    dim3 g1((KKc + BN - 1) / BN, BB / BM);
    gemm_silu_kernel<<<g1, dim3(256), 0, stream>>>(x, W, bias, v);
  }
  expm_kernel<<<dim3(BB), dim3(256), 0, stream>>>(v, out);
}

// Round 6
// 309.836 us; speedup vs baseline: 3.7134x; 1.0250x over previous
//
#include <hip/hip_runtime.h>
#include <hip/hip_bf16.h>
#include <math.h>

#define BB 8192
#define NF 1024
#define KKc 2016
#define DD 64

typedef unsigned short u16;
typedef __attribute__((ext_vector_type(4))) float f32x4;
typedef __attribute__((ext_vector_type(4))) unsigned int u32x4;
typedef __attribute__((ext_vector_type(8))) short s16x8;
typedef __attribute__((ext_vector_type(8))) unsigned short u16x8;

__device__ __forceinline__ u16 bf16_rne(float f) {
  unsigned u = __float_as_uint(f);
  return (u16)((u + 0x7fffu + ((u >> 16) & 1u)) >> 16);
}

union BF2U { __hip_bfloat162 b; unsigned u; };

// packed f32x2 -> bf16x2 (v_cvt_pk_bf16_f32), also return the rounded-back floats
__device__ __forceinline__ unsigned pk_hi(float a, float b, float& fa, float& fb) {
  BF2U r; r.b = __float22bfloat162_rn(make_float2(a, b));
  float2 f = __bfloat1622float2(r.b);
  fa = f.x; fb = f.y;
  return r.u;
}
__device__ __forceinline__ unsigned pk(float a, float b) {
  BF2U r; r.b = __float22bfloat162_rn(make_float2(a, b));
  return r.u;
}

// split quad -> 2 u32 of hi-bf16 + 2 u32 of lo-bf16
__device__ __forceinline__ void split4(const f32x4 v, uint2& h, uint2& l) {
  float f0, f1, f2, f3;
  h.x = pk_hi(v[0], v[1], f0, f1);
  h.y = pk_hi(v[2], v[3], f2, f3);
  l.x = pk(v[0] - f0, v[1] - f1);
  l.y = pk(v[2] - f2, v[3] - f3);
}

// ---------------- Prepass A: xh/xl = split(silu(x)) ----------------
__global__ __launch_bounds__(256)
void silu_split_kernel(const float* __restrict__ x, u16* __restrict__ xh, u16* __restrict__ xl) {
  const int idx = blockIdx.x * 256 + threadIdx.x;
  float4 vv = ((const float4*)x)[idx];
  float a[4] = {vv.x, vv.y, vv.z, vv.w};
  u16 h[4], lo[4];
#pragma unroll
  for (int i = 0; i < 4; i++) {
    const float s = a[i] / (1.f + __expf(-a[i]));
    const u16 hh = bf16_rne(s);
    h[i] = hh;
    lo[i] = bf16_rne(s - __uint_as_float(((unsigned)hh) << 16));
  }
  ((ushort4*)xh)[idx] = make_ushort4(h[0], h[1], h[2], h[3]);
  ((ushort4*)xl)[idx] = make_ushort4(lo[0], lo[1], lo[2], lo[3]);
}

// ---------------- Prepass B: wh/wl = split(W), padded to 2048 rows ----------------
__global__ __launch_bounds__(256)
void wsplit_kernel(const float* __restrict__ W, u16* __restrict__ wh, u16* __restrict__ wl) {
  const int idx = blockIdx.x * 256 + threadIdx.x;
  const int row = idx >> 8;
  float4 vv = make_float4(0.f, 0.f, 0.f, 0.f);
  if (row < KKc) vv = ((const float4*)W)[idx];
  float a[4] = {vv.x, vv.y, vv.z, vv.w};
  u16 h[4], lo[4];
#pragma unroll
  for (int i = 0; i < 4; i++) {
    const u16 hh = bf16_rne(a[i]);
    h[i] = hh;
    lo[i] = bf16_rne(a[i] - __uint_as_float(((unsigned)hh) << 16));
  }
  ((ushort4*)wh)[idx] = make_ushort4(h[0], h[1], h[2], h[3]);
  ((ushort4*)wl)[idx] = make_ushort4(lo[0], lo[1], lo[2], lo[3]);
}

// ---------------- Kernel 1: v = silu(x)@W^T + b via split-bf16 MFMA ----------------
typedef __attribute__((address_space(1))) const unsigned int gu32;
typedef __attribute__((address_space(3))) unsigned int lu32;

__device__ __forceinline__ void gload_lds16(const void* g, void* l) {
  __builtin_amdgcn_global_load_lds((gu32*)g, (lu32*)l, 16, 0, 0);
}

__device__ __forceinline__ s16x8 frag_row32(const u16* T, int row, int kc) {
  const int c = kc ^ ((row >> 1) & 3);
  return *(const s16x8*)(T + row * 32 + c * 8);
}

__global__ __launch_bounds__(256, 3)
void gemm_mfma_kernel(const u16* __restrict__ xh, const u16* __restrict__ xl,
                      const u16* __restrict__ wh, const u16* __restrict__ wl,
                      const float* __restrict__ bias, float* __restrict__ v) {
  __shared__ __align__(16) u16 Ah[128 * 32];
  __shared__ __align__(16) u16 Al[128 * 32];
  __shared__ __align__(16) u16 Bh[128 * 32];
  __shared__ __align__(16) u16 Bl[128 * 32];
  const int tid = threadIdx.x;
  const int l = tid & 63, w = tid >> 6;
  const int wi = w >> 1, wj = w & 1;
  const int m0 = blockIdx.y * 128;
  const int n0 = blockIdx.x * 128;
  const int kc = l >> 4, lr = l & 15;

  const int row0 = (w < 2) ? m0 : n0;
  const u16* P = (w == 0) ? xh : (w == 1) ? xl : (w == 2) ? wh : wl;
  u16* T = (w == 0) ? Ah : (w == 1) ? Al : (w == 2) ? Bh : Bl;

  f32x4 acc[4][4];
  const f32x4 zz = {0.f, 0.f, 0.f, 0.f};
#pragma unroll
  for (int a = 0; a < 4; a++)
#pragma unroll
    for (int b = 0; b < 4; b++) acc[a][b] = zz;

  for (int k0 = 0; k0 < NF; k0 += 32) {
#pragma unroll
    for (int c8 = 0; c8 < 8; c8++) {
      const int slot = c8 * 64 + l;
      const int r = slot >> 2;
      const int c = (slot & 3) ^ ((r >> 1) & 3);
      gload_lds16(P + (size_t)(row0 + r) * NF + k0 + c * 8, T + c8 * 512);
    }
    __syncthreads();

    s16x8 fah[4], fal[4];
#pragma unroll
    for (int a = 0; a < 4; a++) {
      const int ra = wi * 64 + a * 16 + lr;
      fah[a] = frag_row32(Ah, ra, kc);
      fal[a] = frag_row32(Al, ra, kc);
    }
#pragma unroll
    for (int b = 0; b < 4; b++) {
      const int rb = wj * 64 + b * 16 + lr;
      const s16x8 fbh = frag_row32(Bh, rb, kc);
      const s16x8 fbl = frag_row32(Bl, rb, kc);
#pragma unroll
      for (int a = 0; a < 4; a++) {
        acc[a][b] = __builtin_amdgcn_mfma_f32_16x16x32_bf16(fah[a], fbh, acc[a][b], 0, 0, 0);
        acc[a][b] = __builtin_amdgcn_mfma_f32_16x16x32_bf16(fah[a], fbl, acc[a][b], 0, 0, 0);
        acc[a][b] = __builtin_amdgcn_mfma_f32_16x16x32_bf16(fal[a], fbh, acc[a][b], 0, 0, 0);
      }
    }
    __syncthreads();
  }

  const int grp = l >> 4;
#pragma unroll
  for (int b = 0; b < 4; b++) {
    const int n = n0 + wj * 64 + b * 16 + lr;
    if (n < KKc) {
      const float bb = bias[n];
#pragma unroll
      for (int a = 0; a < 4; a++) {
        const int mbase = m0 + wi * 64 + a * 16 + grp * 4;
#pragma unroll
        for (int i = 0; i < 4; i++)
          v[(size_t)(mbase + i) * KKc + n] = acc[a][b][i] + bb;
      }
    }
  }
}

// ---------------- Fallback fp32 GEMM (if ws too small) ----------------
#define BM 128
#define BN 128
#define BKr 16
#define XST 132

__global__ __launch_bounds__(256, 2)
void gemm_silu_kernel(const float* __restrict__ x, const float* __restrict__ W,
                      const float* __restrict__ bias, float* __restrict__ v) {
  __shared__ float xs[BKr * XST];
  __shared__ float wl[BKr * XST];
  const int tid = threadIdx.x;
  const int tx = tid & 15, ty = tid >> 4;
  const int c0g = blockIdx.x * BN;
  const int m0 = blockIdx.y * BM;
  const int lrow = tid >> 2;
  const int lu = (tid & 3) << 2;

  float acc[2][2][4][4];
#pragma unroll
  for (int a = 0; a < 2; a++)
#pragma unroll
    for (int b = 0; b < 2; b++)
#pragma unroll
      for (int i = 0; i < 4; i++)
#pragma unroll
        for (int j = 0; j < 4; j++) acc[a][b][i][j] = 0.f;

  for (int n0 = 0; n0 < NF; n0 += BKr) {
#pragma unroll
    for (int p = 0; p < 2; p++) {
      const int row = lrow + 64 * p;
      float4 xv = *(const float4*)(x + (size_t)(m0 + row) * NF + n0 + lu);
      float xa[4] = {xv.x, xv.y, xv.z, xv.w};
#pragma unroll
      for (int u = 0; u < 4; u++) {
        const float val = xa[u];
        xs[(lu + u) * XST + row] = val / (1.f + __expf(-val));
      }
      const int wr = c0g + row;
      float4 wv = make_float4(0.f, 0.f, 0.f, 0.f);
      if (wr < KKc) wv = *(const float4*)(W + (size_t)wr * NF + n0 + lu);
      float wa[4] = {wv.x, wv.y, wv.z, wv.w};
#pragma unroll
      for (int u = 0; u < 4; u++) wl[(lu + u) * XST + row] = wa[u];
    }
    __syncthreads();
#pragma unroll
    for (int k0 = 0; k0 < BKr; k0 += 4) {
#pragma unroll
      for (int kk = 0; kk < 4; kk++) {
        const float* xr = xs + (k0 + kk) * XST;
        const float* wr_ = wl + (k0 + kk) * XST;
        float4 t;
        t = *(const float4*)(xr + 4 * ty);       float a0[4] = {t.x, t.y, t.z, t.w};
        t = *(const float4*)(xr + 64 + 4 * ty);  float a1[4] = {t.x, t.y, t.z, t.w};
        t = *(const float4*)(wr_ + 4 * tx);      float b0[4] = {t.x, t.y, t.z, t.w};
        t = *(const float4*)(wr_ + 64 + 4 * tx); float b1[4] = {t.x, t.y, t.z, t.w};
#pragma unroll
        for (int i = 0; i < 4; i++)
#pragma unroll
          for (int j = 0; j < 4; j++) {
            acc[0][0][i][j] = fmaf(a0[i], b0[j], acc[0][0][i][j]);
            acc[0][1][i][j] = fmaf(a0[i], b1[j], acc[0][1][i][j]);
            acc[1][0][i][j] = fmaf(a1[i], b0[j], acc[1][0][i][j]);
            acc[1][1][i][j] = fmaf(a1[i], b1[j], acc[1][1][i][j]);
          }
      }
    }
    __syncthreads();
  }
#pragma unroll
  for (int rb = 0; rb < 2; rb++)
#pragma unroll
    for (int ii = 0; ii < 4; ii++) {
      const int row = m0 + rb * 64 + 4 * ty + ii;
#pragma unroll
      for (int cb = 0; cb < 2; cb++) {
        const int c = c0g + cb * 64 + 4 * tx;
        if (c < KKc) {
          float4 bb = *(const float4*)(bias + c);
          float4 o;
          o.x = acc[rb][cb][ii][0] + bb.x;
          o.y = acc[rb][cb][ii][1] + bb.y;
          o.z = acc[rb][cb][ii][2] + bb.z;
          o.w = acc[rb][cb][ii][3] + bb.w;
          *(float4*)(v + (size_t)row * KKc + c) = o;
        }
      }
    }
}

// ---------------- Kernel 2: R = expm(skew(v_row)) — separate hi/lo bf16 planes ----------------
// LDS layout per plane: u16[64][64], 16B chunk swizzle: chunk' = chunk ^ (row&7).

union FragX { u16x8 u; s16x8 s; u32x4 d; };

__device__ __forceinline__ s16x8 fragld(const u16* P, int row, int chunk) {
  return *(const s16x8*)(P + ((row << 6) | ((chunk ^ (row & 7)) << 3)));
}

__device__ __forceinline__ s16x8 fneg(s16x8 f) {
  FragX x; x.s = f;
  x.d ^= (u32x4){0x80008000u, 0x80008000u, 0x80008000u, 0x80008000u};
  return x.s;
}

// acc += A*B (2x2 16x16 tiles/wave); B row-read (symmetric / col-copy / skew+NEGB)
template<int NPASS, bool NEGB>
__device__ __forceinline__ void mat_mm(const u16* APh, const u16* APl,
                                       const u16* BPh, const u16* BPl,
                                       f32x4 acc[2][2], int wi, int wj, int g, int lr) {
#pragma unroll
  for (int kb = 0; kb < 2; kb++) {
    const int ch = (kb << 2) | g;
    s16x8 bh[2], bl[2];
#pragma unroll
    for (int b = 0; b < 2; b++) {
      const int n = wj * 32 + b * 16 + lr;
      bh[b] = fragld(BPh, n, ch);
      if (NEGB) bh[b] = fneg(bh[b]);
      if (NPASS == 3) {
        bl[b] = fragld(BPl, n, ch);
        if (NEGB) bl[b] = fneg(bl[b]);
      }
    }
#pragma unroll
    for (int a = 0; a < 2; a++) {
      const int r = wi * 32 + a * 16 + lr;
      const s16x8 ah = fragld(APh, r, ch);
      s16x8 al;
      if (NPASS == 3) al = fragld(APl, r, ch);
#pragma unroll
      for (int b = 0; b < 2; b++) {
        acc[a][b] = __builtin_amdgcn_mfma_f32_16x16x32_bf16(ah, bh[b], acc[a][b], 0, 0, 0);
        if (NPASS == 3) {
          acc[a][b] = __builtin_amdgcn_mfma_f32_16x16x32_bf16(ah, bl[b], acc[a][b], 0, 0, 0);
          acc[a][b] = __builtin_amdgcn_mfma_f32_16x16x32_bf16(al, bh[b], acc[a][b], 0, 0, 0);
        }
      }
    }
  }
}

// fused 1-pass: acc6 += A4*A2, acc8 += A4*A4 (shared A-frags)
__device__ __forceinline__ void mat_mm68(const u16* A4h, const u16* A2h,
                                         f32x4 acc6[2][2], f32x4 acc8[2][2],
                                         int wi, int wj, int g, int lr) {
#pragma unroll
  for (int kb = 0; kb < 2; kb++) {
    const int ch = (kb << 2) | g;
    s16x8 b2[2], b4[2];
#pragma unroll
    for (int b = 0; b < 2; b++) {
      const int n = wj * 32 + b * 16 + lr;
      b2[b] = fragld(A2h, n, ch);
      b4[b] = fragld(A4h, n, ch);
    }
#pragma unroll
    for (int a = 0; a < 2; a++) {
      const int r = wi * 32 + a * 16 + lr;
      const s16x8 ah = fragld(A4h, r, ch);
#pragma unroll
      for (int b = 0; b < 2; b++) {
        acc6[a][b] = __builtin_amdgcn_mfma_f32_16x16x32_bf16(ah, b2[b], acc6[a][b], 0, 0, 0);
        acc8[a][b] = __builtin_amdgcn_mfma_f32_16x16x32_bf16(ah, b4[b], acc8[a][b], 0, 0, 0);
      }
    }
  }
}

// write acc as [col][row] copy (b64 contiguous). For SYMMETRIC matrices this IS row-major.
__device__ __forceinline__ void pack_col(u16* Ch, u16* Cl, const f32x4 acc[2][2],
                                         int wi, int wj, int g, int lr) {
#pragma unroll
  for (int a = 0; a < 2; a++) {
    const int r0 = wi * 32 + a * 16 + g * 4;
#pragma unroll
    for (int b = 0; b < 2; b++) {
      const int c = wj * 32 + b * 16 + lr;
      uint2 h, l;
      split4(acc[a][b], h, l);
      const int ad = (c << 6) | (((((r0 >> 3)) ^ (c & 7)) << 3) | (r0 & 7));
      *(uint2*)(Ch + ad) = h;
      *(uint2*)(Cl + ad) = l;
    }
  }
}

// write acc to BOTH row-major copy (scalar b16) and col-major copy (b64)
__device__ __forceinline__ void pack_dual(u16* Rh, u16* Rl, u16* Ch, u16* Cl,
                                          const f32x4 acc[2][2], int wi, int wj, int g, int lr) {
#pragma unroll
  for (int a = 0; a < 2; a++) {
    const int r0 = wi * 32 + a * 16 + g * 4;
#pragma unroll
    for (int b = 0; b < 2; b++) {
      const int c = wj * 32 + b * 16 + lr;
      uint2 h, l;
      split4(acc[a][b], h, l);
      const int adc = (c << 6) | (((((r0 >> 3)) ^ (c & 7)) << 3) | (r0 & 7));
      *(uint2*)(Ch + adc) = h;
      *(uint2*)(Cl + adc) = l;
      const u16 ha[4] = {(u16)h.x, (u16)(h.x >> 16), (u16)h.y, (u16)(h.y >> 16)};
      const u16 la[4] = {(u16)l.x, (u16)(l.x >> 16), (u16)l.y, (u16)(l.y >> 16)};
#pragma unroll
      for (int i = 0; i < 4; i++) {
        const int r = r0 + i;
        const int adr = (r << 6) | ((((c >> 3) ^ (r & 7)) << 3) | (c & 7));
        Rh[adr] = ha[i];
        Rl[adr] = la[i];
      }
    }
  }
}

__global__ __launch_bounds__(256, 3)
void expm_kernel(const float* __restrict__ v, float* __restrict__ out) {
  __shared__ __align__(16) u16 Ahs[4096], Als[4096];
  __shared__ __align__(16) u16 P1h[4096], P1l[4096];
  __shared__ __align__(16) u16 P2h[4096], P2l[4096];
  __shared__ float red[4];
  const int tid = threadIdx.x;
  const int bid = blockIdx.x;
  const int l = tid & 63, w = tid >> 6;
  const int g = l >> 4, lr = l & 15;
  const int wi = w >> 1, wj = w & 1;

  // 1. stage v row into P2h (2016 floats, 8064B fits the 8KB plane)
  {
    float* vb = (float*)P2h;
    const float* vr = v + (size_t)bid * KKc;
    for (int i = tid; i < KKc; i += 256) vb[i] = vr[i];
  }
  __syncthreads();

  // 2. build skew A (UNSCALED) into Ah/Al planes via cvt_pk
  {
    const float* vb = (const float*)P2h;
    const int arow = tid >> 2, q = tid & 3;
    float va[16];
#pragma unroll
    for (int j = 0; j < 16; j++) {
      const int c = q * 16 + j;
      float val = 0.f;
      if (arow < c)      val =  vb[(arow * (127 - arow)) / 2 + c - arow - 1];
      else if (arow > c) val = -vb[(c * (127 - c)) / 2 + arow - c - 1];
      va[j] = val;
    }
#pragma unroll
    for (int cc = 0; cc < 2; cc++) {
      const int ch = 2 * q + cc;
      const int ad = (arow << 6) | ((ch ^ (arow & 7)) << 3);
      unsigned hw[4], lw[4];
#pragma unroll
      for (int p = 0; p < 4; p++) {
        const float a = va[cc * 8 + 2 * p], b = va[cc * 8 + 2 * p + 1];
        float fa, fb;
        hw[p] = pk_hi(a, b, fa, fb);
        lw[p] = pk(a - fa, b - fb);
      }
      *(u32x4*)(Ahs + ad) = (u32x4){hw[0], hw[1], hw[2], hw[3]};
      *(u32x4*)(Als + ad) = (u32x4){lw[0], lw[1], lw[2], lw[3]};
    }
  }
  __syncthreads();

  const f32x4 zz = {0.f, 0.f, 0.f, 0.f};
  f32x4 acc[2][2];

  // 3. A2 = A*A (B-frag = -(row-read of skew A))
  acc[0][0] = zz; acc[0][1] = zz; acc[1][0] = zz; acc[1][1] = zz;
  mat_mm<3, true>(Ahs, Als, Ahs, Als, acc, wi, wj, g, lr);
  f32x4 rA2[2][2];
  rA2[0][0] = acc[0][0]; rA2[0][1] = acc[0][1]; rA2[1][0] = acc[1][0]; rA2[1][1] = acc[1][1];
  pack_col(P1h, P1l, acc, wi, wj, g, lr);   // A2 symmetric -> col-copy == row-major
  __syncthreads();

  // 4. A4 = A2*A2
  acc[0][0] = zz; acc[0][1] = zz; acc[1][0] = zz; acc[1][1] = zz;
  mat_mm<3, false>(P1h, P1l, P1h, P1l, acc, wi, wj, g, lr);
  f32x4 rA4[2][2];
  rA4[0][0] = acc[0][0]; rA4[0][1] = acc[0][1]; rA4[1][0] = acc[1][0]; rA4[1][1] = acc[1][1];
  pack_col(P2h, P2l, acc, wi, wj, g, lr);   // A4 symmetric (v-staging dead)
  __syncthreads();

  // 5. A6 = A4*A2, A8 = A4*A4 (fused 1-pass, acc-only)
  f32x4 acc6[2][2], acc8[2][2];
  acc6[0][0] = zz; acc6[0][1] = zz; acc6[1][0] = zz; acc6[1][1] = zz;
  acc8[0][0] = zz; acc8[0][1] = zz; acc8[1][0] = zz; acc8[1][1] = zz;
  mat_mm68(P2h, P1h, acc6, acc8, wi, wj, g, lr);

  // 6. s from ||A^8||_F (tightest cheap bound: lambda_max <= ||A^8||_F^{1/8})
  {
    float fs = 0.f;
#pragma unroll
    for (int a = 0; a < 2; a++)
#pragma unroll
      for (int b = 0; b < 2; b++)
#pragma unroll
        for (int i = 0; i < 4; i++) fs = fmaf(acc8[a][b][i], acc8[a][b][i], fs);
#pragma unroll
    for (int k = 1; k < 64; k <<= 1) fs += __shfl_xor(fs, k, 64);
    if (l == 0) red[w] = fs;
  }
  __syncthreads();   // also: all P1/P2 reads (A6/A8) done before S3' overwrite below

  const float nf16 = red[0] + red[1] + red[2] + red[3];  // = ||A^8||_F^2
  int s = 0;
  if (nf16 > 1.f) {
    s = (int)ceilf(0.0625f * log2f(nf16));
    if (s < 0) s = 0;
    if (s > 15) s = 15;
  }
  const float t = exp2f(-(float)s);
  const float t2 = t * t, t4 = t2 * t2, t6 = t4 * t2, t8 = t4 * t4;
  const float e2 = 0.5f * t2, e4 = t4 / 24.f, e6 = t6 / 720.f, e8 = t8 / 40320.f;
  const float o1 = t, o3 = t * t2 / 6.f, o5 = t * t4 / 120.f, o7 = t * t6 / 5040.f;

  // 7. fold E and S3' from A2,A4,A6,A8 (X^{2k} = t^{2k} A^{2k})
  f32x4 rE[2][2], rS3[2][2];
#pragma unroll
  for (int a = 0; a < 2; a++)
#pragma unroll
    for (int b = 0; b < 2; b++)
#pragma unroll
      for (int i = 0; i < 4; i++) {
        const int row = wi * 32 + a * 16 + g * 4 + i;
        const int col = wj * 32 + b * 16 + lr;
        const float dg = (row == col) ? 1.f : 0.f;
        rE[a][b][i]  = dg + e2 * rA2[a][b][i] + e4 * rA4[a][b][i]
                          + e6 * acc6[a][b][i] + e8 * acc8[a][b][i];
        rS3[a][b][i] = o1 * dg + o3 * rA2[a][b][i] + o5 * rA4[a][b][i]
                              + o7 * acc6[a][b][i];
      }

  pack_col(P1h, P1l, rS3, wi, wj, g, lr);  // S3' symmetric -> P1
  __syncthreads();

  // 8. R0 = E + A * S3'   (acc init = E; S3' carries the t scale)
  acc[0][0] = rE[0][0]; acc[0][1] = rE[0][1]; acc[1][0] = rE[1][0]; acc[1][1] = rE[1][1];
  mat_mm<3, false>(Ahs, Als, P1h, P1l, acc, wi, wj, g, lr);
  __syncthreads();   // all reads of Ah/P1 done before squaring overwrites

  // 9. s squarings: row-copy in P2, col-copy in Ahs
  for (int it = 0; it < s; it++) {
    pack_dual(P2h, P2l, Ahs, Als, acc, wi, wj, g, lr);
    __syncthreads();
    acc[0][0] = zz; acc[0][1] = zz; acc[1][0] = zz; acc[1][1] = zz;
    mat_mm<3, false>(P2h, P2l, Ahs, Als, acc, wi, wj, g, lr);
    __syncthreads();
  }

  // 10. store result
  float* ob = out + (size_t)bid * 4096;
#pragma unroll
  for (int a = 0; a < 2; a++)
#pragma unroll
    for (int b = 0; b < 2; b++)
#pragma unroll
      for (int i = 0; i < 4; i++) {
        const int row = wi * 32 + a * 16 + g * 4 + i;
        const int col = wj * 32 + b * 16 + lr;
        ob[row * 64 + col] = acc[a][b][i];
      }
}

extern "C" void kernel_launch(void* const* d_in, const int* in_sizes, int n_in,
                              void* d_out, int out_size, void* d_ws, size_t ws_size,
                              hipStream_t stream) {
  const float* x = (const float*)d_in[0];
  const float* W = (const float*)d_in[1];
  const float* bias = (const float*)d_in[2];
  float* out = (float*)d_out;
  char* ws = (char*)d_ws;
  float* v = (float*)ws;

  const size_t V_BYTES  = (size_t)BB * KKc * 4;
  const size_t XH_ELEMS = (size_t)BB * NF;
  const size_t WH_ELEMS = (size_t)2048 * NF;
  const size_t NEED = V_BYTES + 2 * XH_ELEMS * 2 + 2 * WH_ELEMS * 2;

  if (ws_size >= NEED) {
    u16* xh = (u16*)(ws + V_BYTES);
    u16* xl = xh + XH_ELEMS;
    u16* wh = xl + XH_ELEMS;
    u16* wlp = wh + WH_ELEMS;
    silu_split_kernel<<<dim3(BB * NF / 4 / 256), dim3(256), 0, stream>>>(x, xh, xl);
    wsplit_kernel<<<dim3(2048 * NF / 4 / 256), dim3(256), 0, stream>>>(W, wh, wlp);
    gemm_mfma_kernel<<<dim3(16, 64), dim3(256), 0, stream>>>(xh, xl, wh, wlp, bias, v);
  } else {
    dim3 g1((KKc + BN - 1) / BN, BB / BM);
    gemm_silu_kernel<<<g1, dim3(256), 0, stream>>>(x, W, bias, v);
  }
  expm_kernel<<<dim3(BB), dim3(256), 0, stream>>>(v, out);
}